// Round 3
// baseline (46381.714 us; speedup 1.0000x reference)
//
#include <hip/hip_runtime.h>
#include <hip/hip_bf16.h>

// Bidirectional 2-layer LSTM, persistent single-kernel implementation.
// I=256, H=512, L=2, D=2, O=8, B=64, S=512.
//
// Round 10 = round 9 re-flight (r8's (256,1) hard-hang wedged the node; r9
// likely never ran). XCD-local L2 handshake with hang-hardening:
//  - __launch_bounds__(256,2): r7-proven co-residency for the 256-WG barrier.
//  - Fast path gated on runtime XCD check: per-residue-class uniformity AND
//    8 distinct XCD ids across the 8 classes (broken/constant s_getreg ->
//    slow path = r7 agent/IF protocol, known-good 7.86 ms).
//  - Bounded waits: step polls ~30 ms worst (latched), phase barrier ~120 ms
//    worst; a broken protocol ends as a fast wrong-answer run with counters.
// Fast path: h stores PLAIN (write-through L1 -> XCD L2, ~250cy vs ~900cy IF),
// flag stores PLAIN, polls via sc0 loads (L1-bypass, L2-hit). Cross-XCD
// visibility only at the 3 phase fences (buffer_wbl2/buffer_inv), the same
// mechanism the prologue's plain stores already rely on.

typedef __attribute__((ext_vector_type(8))) __bf16 bf16x8;
typedef __attribute__((ext_vector_type(4))) float f32x4;

struct Params {
  const float *input_seq, *h0, *c0;
  const float *w_ih_0f, *w_hh_0f, *b_0f;
  const float *w_ih_0b, *w_hh_0b, *b_0b;
  const float *w_ih_1f, *w_hh_1f, *b_1f;
  const float *w_ih_1b, *w_hh_1b, *b_1b;
  const float *fc_w, *fc_b;
  float* out;
  unsigned* flags;        // [0,256): phase slots; [512,768): xcd table
  unsigned* stepf;        // [12 groups][32 producers][16 u32] monotonic flags, 64B/producer
  __bf16* xT;             // [512][64][256]  time-major bf16 input
  __bf16* Wp0f; __bf16* Wp0b;   // [2048 perm rows][768 = 512 hh | 256 ih]
  __bf16* Wp1f; __bf16* Wp1b;   // [2048 perm rows][1536 = 512 hh | 1024 ih]
  __bf16* y0;             // [514][64][1024]; slab s = t+1; slab0/513 = inits (write-once)
  __bf16* y1f;            // [513][64][512]; slab t+1 = h1f(t); slab0 = h0[2] init (write-once)
  __bf16* h1binit;        // [64][512]
  __bf16* h1bout;         // [64][512]
  float* bp;              // [4][2048] permuted biases (0f,0b,1f,1b)
};

__device__ __forceinline__ float sigm(float x) { return 1.f / (1.f + __expf(-x)); }
__device__ __forceinline__ float tanh_fast(float x) {
  // tanh(x) = 1 - 2/(1+e^{2x}); saturates correctly for |x| large.
  return 1.f - 2.f / (1.f + __expf(2.f * x));
}

// Phase barrier (3 uses): agent-scope; release fence writes back dirty L2
// (buffer_wbl2) so plain stores become cross-XCD visible; acquire invalidates.
// Timeout ~200K rounds (~120 ms): deadlock -> clean fail, not a wedge.
__device__ __forceinline__ void phase_barrier(unsigned* pf, int wg, int tid, unsigned phase) {
  __syncthreads();
  if (tid == 0) {
    __builtin_amdgcn_fence(__ATOMIC_RELEASE, "agent");
    __hip_atomic_store(pf + wg, phase, __ATOMIC_RELAXED, __HIP_MEMORY_SCOPE_AGENT);
  }
  bool ok;
  unsigned it = 0;
  do {
    unsigned v = __hip_atomic_load(pf + tid, __ATOMIC_RELAXED, __HIP_MEMORY_SCOPE_AGENT);
    ok = (v >= phase) || (++it > 200000u);
    if (!ok) __builtin_amdgcn_s_sleep(8);
  } while (!__syncthreads_and(ok));
  __builtin_amdgcn_fence(__ATOMIC_ACQUIRE, "agent");
}

// Wave 0: lanes 0..31 poll 32 producer flag lines (64B stride) in parallel.
// fast: sc0 load (bypass L1, read same-XCD L2). slow: agent/IF (r7 behavior).
// Returns false on timeout (~200K rounds ~30 ms); caller latches and stops.
__device__ __forceinline__ bool group_wait32(const unsigned* base, int lane,
                                             unsigned need, bool fast) {
  for (unsigned it = 0;; ++it) {
    bool ok = true;
    if (lane < 32) {
      unsigned v;
      if (fast) {
        const unsigned* a = base + (size_t)lane * 16;
        asm volatile("global_load_dword %0, %1, off sc0\n\ts_waitcnt vmcnt(0)"
                     : "=v"(v) : "v"(a) : "memory");
      } else {
        v = __hip_atomic_load(base + (size_t)lane * 16, __ATOMIC_RELAXED,
                              __HIP_MEMORY_SCOPE_AGENT);
      }
      ok = v >= need;
    }
    if (__ballot(ok) == ~0ull) break;
    if (it > 200000u) return false;
    __builtin_amdgcn_s_sleep(1);
  }
  asm volatile("" ::: "memory");   // no hoisting of h loads above the poll
  return true;
}

__device__ __forceinline__ void flag_store(unsigned* a, unsigned v, bool fast) {
  if (fast) __hip_atomic_store(a, v, __ATOMIC_RELAXED, __HIP_MEMORY_SCOPE_WORKGROUP);
  else      __hip_atomic_store(a, v, __ATOMIC_RELAXED, __HIP_MEMORY_SCOPE_AGENT);
}

// Pointwise for one step: 64 lanes, one hidden unit each (b=lane>>2, u=lane&3).
// fast: plain u64 store (write-through to same-XCD L2; phase fences publish
// cross-XCD later). slow: agent/IF store (r7 behavior).
__device__ __forceinline__ void pointwise_store(float* ldsw, int lane, float& c,
                                                __bf16* rowbase_u0, bool fast) {
  f32x4 g4 = *(const f32x4*)(ldsw + (lane >> 2) * 20 + (lane & 3) * 4);
  float cj = sigm(g4[1]) * c + sigm(g4[0]) * tanh_fast(g4[2]);
  c = cj;
  float h = sigm(g4[3]) * tanh_fast(cj);
  __bf16 hb = (__bf16)h;
  unsigned short hu; __builtin_memcpy(&hu, &hb, 2);
  unsigned v0 = (unsigned)hu | (__shfl_down((unsigned)hu, 1, 4) << 16);
  unsigned long long pk = (unsigned long long)v0 |
                          ((unsigned long long)__shfl_down(v0, 2, 4) << 32);
  if ((lane & 3) == 0) {
    if (fast)
      __hip_atomic_store((unsigned long long*)rowbase_u0, pk,
                         __ATOMIC_RELAXED, __HIP_MEMORY_SCOPE_WORKGROUP);
    else
      __hip_atomic_store((unsigned long long*)rowbase_u0, pk,
                         __ATOMIC_RELAXED, __HIP_MEMORY_SCOPE_AGENT);
  }
}

__global__ __launch_bounds__(256, 2) void lstm_kernel(Params p) {
  const int tid  = threadIdx.x;
  const int wg   = blockIdx.x;
  const unsigned gtid = wg * 256 + tid;
  const int lane = tid & 63;
  const int wv   = tid >> 6;          // wave 0..3
  const int colq = lane & 15;         // A-operand batch row m / B-operand gate col n
  const int quad = lane >> 4;         // k-subblock selector

  __shared__ float lds[4][320];       // stride 20: aligned f32x4, ~2-way banks
  float* ldsw = lds[wv];              // wave-private slab

  // ---------------- prologue: pack/permute/convert ----------------
  { // publish this WG's XCD id (hwreg id=20 HW_REG_XCC_ID, offset 0, size 32)
    unsigned xcd = __builtin_amdgcn_s_getreg(20 | (31 << 11));
    if (tid == 0) p.flags[512 + wg] = xcd;
  }
  { // xT[t][b][:] = bf16(input_seq[b][t][:])
    int row = gtid >> 1, half = gtid & 1;
    int t = row >> 6, b = row & 63;
    const float* src = p.input_seq + ((size_t)b * 512 + t) * 256 + half * 128;
    __bf16* dst = p.xT + (size_t)row * 256 + half * 128;
    for (int i = 0; i < 128; i += 8) {
      bf16x8 v;
      #pragma unroll
      for (int j = 0; j < 8; ++j) v[j] = (__bf16)src[i + j];
      *(bf16x8*)(dst + i) = v;
    }
  }
  // Wp0{f,b}: [2048][768]; perm row rr: u=rr>>2,g=rr&3, orig row R=g*512+u
  for (unsigned task = gtid; task < 2u * 2048 * 6; task += 65536) {
    unsigned dir = task / (2048 * 6);
    unsigned rr = (task / 6) % 2048;
    unsigned ch = task % 6;
    unsigned R = (rr & 3) * 512 + (rr >> 2);
    const float* wih = dir ? p.w_ih_0b : p.w_ih_0f;
    const float* whh = dir ? p.w_hh_0b : p.w_hh_0f;
    __bf16* dst = (dir ? p.Wp0b : p.Wp0f) + (size_t)rr * 768;
    const float* src; unsigned kd;
    if (ch < 4) { src = whh + (size_t)R * 512 + ch * 128;        kd = ch * 128; }
    else        { src = wih + (size_t)R * 256 + (ch - 4) * 128;  kd = 512 + (ch - 4) * 128; }
    for (int i = 0; i < 128; i += 8) {
      bf16x8 v;
      #pragma unroll
      for (int j = 0; j < 8; ++j) v[j] = (__bf16)src[i + j];
      *(bf16x8*)(dst + kd + i) = v;
    }
  }
  // Wp1{f,b}: [2048][1536]
  for (unsigned task = gtid; task < 2u * 2048 * 12; task += 65536) {
    unsigned dir = task / (2048 * 12);
    unsigned rr = (task / 12) % 2048;
    unsigned ch = task % 12;
    unsigned R = (rr & 3) * 512 + (rr >> 2);
    const float* wih = dir ? p.w_ih_1b : p.w_ih_1f;
    const float* whh = dir ? p.w_hh_1b : p.w_hh_1f;
    __bf16* dst = (dir ? p.Wp1b : p.Wp1f) + (size_t)rr * 1536;
    const float* src; unsigned kd;
    if (ch < 4) { src = whh + (size_t)R * 512 + ch * 128;         kd = ch * 128; }
    else        { src = wih + (size_t)R * 1024 + (ch - 4) * 128;  kd = 512 + (ch - 4) * 128; }
    for (int i = 0; i < 128; i += 8) {
      bf16x8 v;
      #pragma unroll
      for (int j = 0; j < 8; ++j) v[j] = (__bf16)src[i + j];
      *(bf16x8*)(dst + kd + i) = v;
    }
  }
  // permuted biases
  if (gtid < 4u * 2048) {
    unsigned arr = gtid >> 11, rr = gtid & 2047;
    unsigned R = (rr & 3) * 512 + (rr >> 2);
    const float* src = arr == 0 ? p.b_0f : arr == 1 ? p.b_0b : arr == 2 ? p.b_1f : p.b_1b;
    p.bp[arr * 2048 + rr] = src[R];
  }
  // h inits (bf16): y0 slab0 lo=h0[0]; y0 slab513 hi=h0[1]; y1f slab0=h0[2]; h1binit=h0[3]
  if (gtid < 4u * 4096) {
    unsigned dl = gtid >> 12;
    unsigned e = (gtid & 4095) * 8;
    unsigned b = e >> 9, u = e & 511;
    const float* src = p.h0 + (size_t)dl * 64 * 512 + (size_t)b * 512 + u;
    __bf16* dst;
    if (dl == 0)      dst = p.y0 + ((size_t)0 * 64 + b) * 1024 + u;
    else if (dl == 1) dst = p.y0 + ((size_t)513 * 64 + b) * 1024 + 512 + u;
    else if (dl == 2) dst = p.y1f + ((size_t)0 * 64 + b) * 512 + u;
    else              dst = p.h1binit + (size_t)b * 512 + u;
    bf16x8 v;
    #pragma unroll
    for (int j = 0; j < 8; ++j) v[j] = (__bf16)src[j];
    *(bf16x8*)dst = v;
  }

  phase_barrier(p.flags, wg, tid, 1u);

  // Fast path requires: my residue class (the 32 WGs I exchange h/flags with)
  // on ONE XCD, and the 8 classes on 8 DISTINCT XCDs (guards a broken getreg
  // that reads a constant -- which would otherwise fake "single-XCD").
  bool fast;
  {
    const unsigned* xt = p.flags + 512;
    const int r = wg & 7;
    unsigned x0 = xt[r];
    bool ok = true;
    for (int k = 1; k < 32; ++k) ok &= (xt[r + 8 * k] == x0);
    unsigned mask = 0;
    for (int rr = 0; rr < 8; ++rr) mask |= 1u << (xt[rr] & 31);
    ok &= (__popc(mask) == 8);
    fast = ok;   // identical across all members of a class
  }

  // ---------------- P1: layer0 recurrence ----------------
  // group g = wg & 7 (fwd: 0..3, bwd: 4..7; bg = g & 3); ug = wg >> 3.
  {
    const int g = wg & 7;
    const bool fwd = g < 4;
    const int bg = g & 3;
    const int ug = wg >> 3;
    const int bbase = bg * 16;
    const int uglob = ug * 16 + wv * 4;  // this wave: 4 hidden units
    const int colbase = uglob * 4;       // 16 permuted gate cols
    const __bf16* Wp = fwd ? p.Wp0f : p.Wp0b;
    bf16x8 wf[24];
    #pragma unroll
    for (int kb = 0; kb < 24; ++kb)
      wf[kb] = *(const bf16x8*)(Wp + (size_t)(colbase + colq) * 768 + kb * 32 + quad * 8);
    const float bias_col = p.bp[(fwd ? 0 : 1) * 2048 + colbase + colq];
    // per-lane c: batch row bbase+(lane>>2), unit uglob+(lane&3)
    float c = p.c0[(size_t)(fwd ? 0 : 1) * 64 * 512 +
                   (size_t)(bbase + (lane >> 2)) * 512 + uglob + (lane & 3)];
    const int dcol = fwd ? 0 : 512;
    unsigned* gfl = p.stepf + (size_t)g * 32 * 16;
    bool alive = true;
    for (int s = 0; s < 512; ++s) {
      const int t = fwd ? s : 511 - s;
      const int slabA = fwd ? t : t + 2;   // h(t-1) at slab t; h(t+1) at slab t+2
      const __bf16* aX = p.xT + ((size_t)t * 64 + bbase + colq) * 256 + quad * 8;
      bf16x8 xf[8];
      const bool pre = (wv != 0) || (s == 0);  // wave 0 defers: keeps poll's vmcnt clean
      if (pre) {
        #pragma unroll
        for (int kb = 0; kb < 8; ++kb) xf[kb] = *(const bf16x8*)(aX + kb * 32);
      }
      if (s > 0) {
        if (wv == 0 && alive) alive = group_wait32(gfl, lane, (unsigned)s, fast);
        __syncthreads();                  // release all 4 waves
      }
      if (!pre) {                         // L1-hot: waves 1..3 already pulled it
        #pragma unroll
        for (int kb = 0; kb < 8; ++kb) xf[kb] = *(const bf16x8*)(aX + kb * 32);
      }
      // h fragments: plain cached (write-once slab; same-XCD L2 in fast path)
      const __bf16* aH = p.y0 + ((size_t)slabA * 64 + bbase + colq) * 1024 + dcol + quad * 8;
      f32x4 acc = {0.f, 0.f, 0.f, 0.f};
      #pragma unroll
      for (int kb = 0; kb < 8; ++kb)
        acc = __builtin_amdgcn_mfma_f32_16x16x32_bf16(xf[kb], wf[16 + kb], acc, 0, 0, 0);
      #pragma unroll
      for (int kb = 0; kb < 16; ++kb)
        acc = __builtin_amdgcn_mfma_f32_16x16x32_bf16(*(const bf16x8*)(aH + kb * 32), wf[kb], acc, 0, 0, 0);
      // acc[r]: batch row quad*4+r, gate col colq -> LDS [batch][gate], stride 20
      #pragma unroll
      for (int r = 0; r < 4; ++r) ldsw[(quad * 4 + r) * 20 + colq] = acc[r] + bias_col;
      pointwise_store(ldsw, lane, c,
        p.y0 + ((size_t)(t + 1) * 64 + bbase + (lane >> 2)) * 1024 + dcol + uglob, fast);
      if (s < 511) {
        asm volatile("s_waitcnt vmcnt(0)" ::: "memory");  // h stores ack'd (L2 fast / IF slow)
        __syncthreads();                                  // all 4 waves drained
        if (tid == 0)                                     // single-writer flag line
          flag_store(gfl + (size_t)ug * 16, (unsigned)(s + 1), fast);
      }
    }
  }
  phase_barrier(p.flags, wg, tid, 2u);

  // ---------------- P3: layer1 fwd ((wg&7)<4) | P4: layer1 bwd single step ----------------
  if ((wg & 7) < 4) {
    const int bg = wg & 7;
    const int ug = wg >> 3;
    const int bbase = bg * 16;
    const int uglob = ug * 16 + wv * 4;
    const int colbase = uglob * 4;
    bf16x8 wf[48];                       // [hh 16 | ih 32] frags
    #pragma unroll
    for (int kb = 0; kb < 48; ++kb)
      wf[kb] = *(const bf16x8*)(p.Wp1f + (size_t)(colbase + colq) * 1536 + kb * 32 + quad * 8);
    const float bias_col = p.bp[2 * 2048 + colbase + colq];
    float c = p.c0[(size_t)2 * 64 * 512 +
                   (size_t)(bbase + (lane >> 2)) * 512 + uglob + (lane & 3)];
    unsigned* gfl = p.stepf + (size_t)(8 + bg) * 32 * 16;
    bool alive = true;
    for (int t = 0; t < 512; ++t) {
      // x = y0 slab t+1 (available since barrier 2)
      const __bf16* aX = p.y0 + ((size_t)(t + 1) * 64 + bbase + colq) * 1024 + quad * 8;
      bf16x8 xf[32];
      const bool pre = (wv != 0) || (t == 0);
      if (pre) {
        #pragma unroll
        for (int kb = 0; kb < 32; ++kb) xf[kb] = *(const bf16x8*)(aX + kb * 32);
      }
      if (t > 0) {
        if (wv == 0 && alive) alive = group_wait32(gfl, lane, (unsigned)t, fast);
        __syncthreads();
      }
      if (!pre) {
        #pragma unroll
        for (int kb = 0; kb < 32; ++kb) xf[kb] = *(const bf16x8*)(aX + kb * 32);
      }
      // h = y1f slab t (write-once; same-XCD L2 in fast path)
      const __bf16* aH = p.y1f + ((size_t)t * 64 + bbase + colq) * 512 + quad * 8;
      f32x4 acc = {0.f, 0.f, 0.f, 0.f};
      #pragma unroll
      for (int kb = 0; kb < 32; ++kb)
        acc = __builtin_amdgcn_mfma_f32_16x16x32_bf16(xf[kb], wf[16 + kb], acc, 0, 0, 0);
      #pragma unroll
      for (int kb = 0; kb < 16; ++kb)
        acc = __builtin_amdgcn_mfma_f32_16x16x32_bf16(*(const bf16x8*)(aH + kb * 32), wf[kb], acc, 0, 0, 0);
      #pragma unroll
      for (int r = 0; r < 4; ++r) ldsw[(quad * 4 + r) * 20 + colq] = acc[r] + bias_col;
      pointwise_store(ldsw, lane, c,
        p.y1f + ((size_t)(t + 1) * 64 + bbase + (lane >> 2)) * 512 + uglob, fast);
      if (t < 511) {
        asm volatile("s_waitcnt vmcnt(0)" ::: "memory");
        __syncthreads();
        if (tid == 0)
          flag_store(gfl + (size_t)ug * 16, (unsigned)(t + 1), fast);
      }
    }
  } else {
    const int bg = (wg & 7) - 4;
    const int ug = wg >> 3;
    const int bbase = bg * 16;
    const int uglob = ug * 16 + wv * 4;
    const int colbase = uglob * 4;
    const __bf16* aH = p.h1binit + (size_t)(bbase + colq) * 512 + quad * 8;
    const __bf16* aX = p.y0 + ((size_t)512 * 64 + bbase + colq) * 1024 + quad * 8;
    const __bf16* wrow = p.Wp1b + (size_t)(colbase + colq) * 1536;
    f32x4 acc = {0.f, 0.f, 0.f, 0.f};
    #pragma unroll
    for (int kb = 0; kb < 16; ++kb)
      acc = __builtin_amdgcn_mfma_f32_16x16x32_bf16(*(const bf16x8*)(aH + kb * 32), *(const bf16x8*)(wrow + kb * 32 + quad * 8), acc, 0, 0, 0);
    #pragma unroll
    for (int kb = 0; kb < 32; ++kb)
      acc = __builtin_amdgcn_mfma_f32_16x16x32_bf16(*(const bf16x8*)(aX + kb * 32), *(const bf16x8*)(wrow + (16 + kb) * 32 + quad * 8), acc, 0, 0, 0);
    const float bias_col = p.bp[3 * 2048 + colbase + colq];
    #pragma unroll
    for (int r = 0; r < 4; ++r) ldsw[(quad * 4 + r) * 20 + colq] = acc[r] + bias_col;
    float c = p.c0[(size_t)3 * 64 * 512 +
                   (size_t)(bbase + (lane >> 2)) * 512 + uglob + (lane & 3)];
    // consumed only after barrier 3 (FC); plain store + fence publication
    pointwise_store(ldsw, lane, c,
      p.h1bout + (size_t)(bbase + (lane >> 2)) * 512 + uglob, true);
  }
  phase_barrier(p.flags, wg, tid, 3u);

  // ---------------- FC: out[b][o] = fc_b[o] + last[b,:] . fc_w[o,:] ----------------
  if (wg < 8) {
    const int b = wg * 8 + (tid >> 5);
    const int o = (tid >> 2) & 7;
    const int ks = tid & 3;
    const int k0 = ks * 256;
    const __bf16* l1 = p.y1f + ((size_t)512 * 64 + b) * 512;   // h1f(t=511) = slab 512
    const __bf16* l2 = p.h1bout + (size_t)b * 512;             // h1b(t=511)
    const __bf16* hsrc = (ks < 2) ? (l1 + k0) : (l2 + k0 - 512);
    const float* w = p.fc_w + (size_t)o * 1024 + k0;
    float acc = 0.f;
    for (int k = 0; k < 256; ++k) acc += (float)hsrc[k] * w[k];
    acc += __shfl_down(acc, 2, 4);
    acc += __shfl_down(acc, 1, 4);
    if (ks == 0) p.out[b * 8 + o] = acc + p.fc_b[o];
  }
}

extern "C" void kernel_launch(void* const* d_in, const int* in_sizes, int n_in,
                              void* d_out, int out_size, void* d_ws, size_t ws_size,
                              hipStream_t stream) {
  char* ws = (char*)d_ws;
  Params p;
  p.input_seq = (const float*)d_in[0];
  p.h0 = (const float*)d_in[1];
  p.c0 = (const float*)d_in[2];
  p.w_ih_0f = (const float*)d_in[3];  p.w_hh_0f = (const float*)d_in[4];  p.b_0f = (const float*)d_in[5];
  p.w_ih_0b = (const float*)d_in[6];  p.w_hh_0b = (const float*)d_in[7];  p.b_0b = (const float*)d_in[8];
  p.w_ih_1f = (const float*)d_in[9];  p.w_hh_1f = (const float*)d_in[10]; p.b_1f = (const float*)d_in[11];
  p.w_ih_1b = (const float*)d_in[12]; p.w_hh_1b = (const float*)d_in[13]; p.b_1b = (const float*)d_in[14];
  p.fc_w = (const float*)d_in[15];    p.fc_b = (const float*)d_in[16];
  p.out = (float*)d_out;

  const size_t STEPF_BYTES = (size_t)12 * 32 * 64;   // 24576
  const size_t SYNC_BYTES = 4096 + STEPF_BYTES;
  size_t off = 0;
  p.flags  = (unsigned*)(ws + off); off += 4096;
  p.stepf  = (unsigned*)(ws + off); off += STEPF_BYTES;
  p.xT     = (__bf16*)(ws + off);   off += (size_t)512 * 64 * 256 * 2;
  p.Wp0f   = (__bf16*)(ws + off);   off += (size_t)2048 * 768 * 2;
  p.Wp0b   = (__bf16*)(ws + off);   off += (size_t)2048 * 768 * 2;
  p.Wp1f   = (__bf16*)(ws + off);   off += (size_t)2048 * 1536 * 2;
  p.Wp1b   = (__bf16*)(ws + off);   off += (size_t)2048 * 1536 * 2;
  p.y0     = (__bf16*)(ws + off);   off += (size_t)514 * 64 * 1024 * 2;
  p.y1f    = (__bf16*)(ws + off);   off += (size_t)513 * 64 * 512 * 2;
  p.h1binit= (__bf16*)(ws + off);   off += (size_t)64 * 512 * 2;
  p.h1bout = (__bf16*)(ws + off);   off += (size_t)64 * 512 * 2;
  p.bp     = (float*)(ws + off);    off += (size_t)4 * 2048 * 4;
  (void)ws_size; (void)in_sizes; (void)n_in; (void)out_size;

  hipMemsetAsync(d_ws, 0, SYNC_BYTES, stream);   // zero phase flags + step flags
  lstm_kernel<<<dim3(256), dim3(256), 0, stream>>>(p);
}

// Round 4
// 8169.318 us; speedup vs baseline: 5.6776x; 5.6776x over previous
//
#include <hip/hip_runtime.h>
#include <hip/hip_bf16.h>

// Bidirectional 2-layer LSTM, persistent single-kernel implementation.
// I=256, H=512, L=2, D=2, O=8, B=64, S=512.
//
// Round 11. r10 post-mortem: fast path engaged (WRITE_SIZE 483->183MB, plain
// stores merged in XCD L2; correctness held) but hops went 7.7us -> ~70us.
// Diagnosis: the poll's hand-rolled `global_load_dword ... sc0` is NOT an
// L1-bypass on gfx950 (sc0/sc1 is a scope encoding); the flag line sat stale
// in the consumer's L1 until eviction (~70us). Stores were prompt.
// Fix: polls use compiler-emitted agent-scope atomic loads (proven prompt in
// r7) in BOTH modes; they pass through the consumer's own XCD L2 and are
// served by the producer's dirty flag line there (same XCD).
// Fast path now: h stores PLAIN (write-through L1 -> XCD L2, drain ~300cy vs
// ~900cy IF), flag stores PLAIN, polls agent-scope, h loads plain (L2-dirty
// hit). Cross-XCD visibility only at the 3 phase fences -- mechanism proven
// by the prologue and by r10's correct cross-phase reads.
// Safety rails kept: XCD table + per-class uniformity + 8-distinct gate
// (fallback = exact r7 agent/IF protocol), bounded waits (no wedge).

typedef __attribute__((ext_vector_type(8))) __bf16 bf16x8;
typedef __attribute__((ext_vector_type(4))) float f32x4;

struct Params {
  const float *input_seq, *h0, *c0;
  const float *w_ih_0f, *w_hh_0f, *b_0f;
  const float *w_ih_0b, *w_hh_0b, *b_0b;
  const float *w_ih_1f, *w_hh_1f, *b_1f;
  const float *w_ih_1b, *w_hh_1b, *b_1b;
  const float *fc_w, *fc_b;
  float* out;
  unsigned* flags;        // [0,256): phase slots; [512,768): xcd table
  unsigned* stepf;        // [12 groups][32 producers][16 u32] monotonic flags, 64B/producer
  __bf16* xT;             // [512][64][256]  time-major bf16 input
  __bf16* Wp0f; __bf16* Wp0b;   // [2048 perm rows][768 = 512 hh | 256 ih]
  __bf16* Wp1f; __bf16* Wp1b;   // [2048 perm rows][1536 = 512 hh | 1024 ih]
  __bf16* y0;             // [514][64][1024]; slab s = t+1; slab0/513 = inits (write-once)
  __bf16* y1f;            // [513][64][512]; slab t+1 = h1f(t); slab0 = h0[2] init (write-once)
  __bf16* h1binit;        // [64][512]
  __bf16* h1bout;         // [64][512]
  float* bp;              // [4][2048] permuted biases (0f,0b,1f,1b)
};

__device__ __forceinline__ float sigm(float x) { return 1.f / (1.f + __expf(-x)); }
__device__ __forceinline__ float tanh_fast(float x) {
  // tanh(x) = 1 - 2/(1+e^{2x}); saturates correctly for |x| large.
  return 1.f - 2.f / (1.f + __expf(2.f * x));
}

// Phase barrier (3 uses): agent-scope; release fence publishes L2-dirty plain
// stores cross-XCD; acquire invalidates. Timeout ~200K rounds: deadlock ->
// clean fail, not a wedge.
__device__ __forceinline__ void phase_barrier(unsigned* pf, int wg, int tid, unsigned phase) {
  __syncthreads();
  if (tid == 0) {
    __builtin_amdgcn_fence(__ATOMIC_RELEASE, "agent");
    __hip_atomic_store(pf + wg, phase, __ATOMIC_RELAXED, __HIP_MEMORY_SCOPE_AGENT);
  }
  bool ok;
  unsigned it = 0;
  do {
    unsigned v = __hip_atomic_load(pf + tid, __ATOMIC_RELAXED, __HIP_MEMORY_SCOPE_AGENT);
    ok = (v >= phase) || (++it > 200000u);
    if (!ok) __builtin_amdgcn_s_sleep(8);
  } while (!__syncthreads_and(ok));
  __builtin_amdgcn_fence(__ATOMIC_ACQUIRE, "agent");
}

// Wave 0: lanes 0..31 poll 32 producer flag lines (64B stride) in parallel.
// Agent-scope atomic load in BOTH modes (L1-bypassed, proven-prompt; served
// by same-XCD L2 dirty line in fast mode, by IF in slow mode).
// Returns false on timeout (~200K rounds); caller latches and stops waiting.
__device__ __forceinline__ bool group_wait32(const unsigned* base, int lane,
                                             unsigned need) {
  for (unsigned it = 0;; ++it) {
    bool ok = true;
    if (lane < 32)
      ok = __hip_atomic_load(base + (size_t)lane * 16, __ATOMIC_RELAXED,
                             __HIP_MEMORY_SCOPE_AGENT) >= need;
    if (__ballot(ok) == ~0ull) break;
    if (it > 200000u) return false;
    __builtin_amdgcn_s_sleep(1);
  }
  asm volatile("" ::: "memory");   // no hoisting of h loads above the poll
  return true;
}

__device__ __forceinline__ void flag_store(unsigned* a, unsigned v, bool fast) {
  // fast: plain write-through store -> XCD L2 (prompt; r10-proven).
  // slow: agent/IF store (r7 protocol).
  if (fast) __hip_atomic_store(a, v, __ATOMIC_RELAXED, __HIP_MEMORY_SCOPE_WORKGROUP);
  else      __hip_atomic_store(a, v, __ATOMIC_RELAXED, __HIP_MEMORY_SCOPE_AGENT);
}

// Pointwise for one step: 64 lanes, one hidden unit each (b=lane>>2, u=lane&3).
// fast: plain u64 store (write-through to same-XCD L2; phase fences publish
// cross-XCD later). slow: agent/IF store (r7 behavior).
__device__ __forceinline__ void pointwise_store(float* ldsw, int lane, float& c,
                                                __bf16* rowbase_u0, bool fast) {
  f32x4 g4 = *(const f32x4*)(ldsw + (lane >> 2) * 20 + (lane & 3) * 4);
  float cj = sigm(g4[1]) * c + sigm(g4[0]) * tanh_fast(g4[2]);
  c = cj;
  float h = sigm(g4[3]) * tanh_fast(cj);
  __bf16 hb = (__bf16)h;
  unsigned short hu; __builtin_memcpy(&hu, &hb, 2);
  unsigned v0 = (unsigned)hu | (__shfl_down((unsigned)hu, 1, 4) << 16);
  unsigned long long pk = (unsigned long long)v0 |
                          ((unsigned long long)__shfl_down(v0, 2, 4) << 32);
  if ((lane & 3) == 0) {
    if (fast)
      __hip_atomic_store((unsigned long long*)rowbase_u0, pk,
                         __ATOMIC_RELAXED, __HIP_MEMORY_SCOPE_WORKGROUP);
    else
      __hip_atomic_store((unsigned long long*)rowbase_u0, pk,
                         __ATOMIC_RELAXED, __HIP_MEMORY_SCOPE_AGENT);
  }
}

__global__ __launch_bounds__(256, 2) void lstm_kernel(Params p) {
  const int tid  = threadIdx.x;
  const int wg   = blockIdx.x;
  const unsigned gtid = wg * 256 + tid;
  const int lane = tid & 63;
  const int wv   = tid >> 6;          // wave 0..3
  const int colq = lane & 15;         // A-operand batch row m / B-operand gate col n
  const int quad = lane >> 4;         // k-subblock selector

  __shared__ float lds[4][320];       // stride 20: aligned f32x4, ~2-way banks
  float* ldsw = lds[wv];              // wave-private slab

  // ---------------- prologue: pack/permute/convert ----------------
  { // publish this WG's XCD id (hwreg id=20 HW_REG_XCC_ID, offset 0, size 32)
    unsigned xcd = __builtin_amdgcn_s_getreg(20 | (31 << 11));
    if (tid == 0) p.flags[512 + wg] = xcd;
  }
  { // xT[t][b][:] = bf16(input_seq[b][t][:])
    int row = gtid >> 1, half = gtid & 1;
    int t = row >> 6, b = row & 63;
    const float* src = p.input_seq + ((size_t)b * 512 + t) * 256 + half * 128;
    __bf16* dst = p.xT + (size_t)row * 256 + half * 128;
    for (int i = 0; i < 128; i += 8) {
      bf16x8 v;
      #pragma unroll
      for (int j = 0; j < 8; ++j) v[j] = (__bf16)src[i + j];
      *(bf16x8*)(dst + i) = v;
    }
  }
  // Wp0{f,b}: [2048][768]; perm row rr: u=rr>>2,g=rr&3, orig row R=g*512+u
  for (unsigned task = gtid; task < 2u * 2048 * 6; task += 65536) {
    unsigned dir = task / (2048 * 6);
    unsigned rr = (task / 6) % 2048;
    unsigned ch = task % 6;
    unsigned R = (rr & 3) * 512 + (rr >> 2);
    const float* wih = dir ? p.w_ih_0b : p.w_ih_0f;
    const float* whh = dir ? p.w_hh_0b : p.w_hh_0f;
    __bf16* dst = (dir ? p.Wp0b : p.Wp0f) + (size_t)rr * 768;
    const float* src; unsigned kd;
    if (ch < 4) { src = whh + (size_t)R * 512 + ch * 128;        kd = ch * 128; }
    else        { src = wih + (size_t)R * 256 + (ch - 4) * 128;  kd = 512 + (ch - 4) * 128; }
    for (int i = 0; i < 128; i += 8) {
      bf16x8 v;
      #pragma unroll
      for (int j = 0; j < 8; ++j) v[j] = (__bf16)src[i + j];
      *(bf16x8*)(dst + kd + i) = v;
    }
  }
  // Wp1{f,b}: [2048][1536]
  for (unsigned task = gtid; task < 2u * 2048 * 12; task += 65536) {
    unsigned dir = task / (2048 * 12);
    unsigned rr = (task / 12) % 2048;
    unsigned ch = task % 12;
    unsigned R = (rr & 3) * 512 + (rr >> 2);
    const float* wih = dir ? p.w_ih_1b : p.w_ih_1f;
    const float* whh = dir ? p.w_hh_1b : p.w_hh_1f;
    __bf16* dst = (dir ? p.Wp1b : p.Wp1f) + (size_t)rr * 1536;
    const float* src; unsigned kd;
    if (ch < 4) { src = whh + (size_t)R * 512 + ch * 128;         kd = ch * 128; }
    else        { src = wih + (size_t)R * 1024 + (ch - 4) * 128;  kd = 512 + (ch - 4) * 128; }
    for (int i = 0; i < 128; i += 8) {
      bf16x8 v;
      #pragma unroll
      for (int j = 0; j < 8; ++j) v[j] = (__bf16)src[i + j];
      *(bf16x8*)(dst + kd + i) = v;
    }
  }
  // permuted biases
  if (gtid < 4u * 2048) {
    unsigned arr = gtid >> 11, rr = gtid & 2047;
    unsigned R = (rr & 3) * 512 + (rr >> 2);
    const float* src = arr == 0 ? p.b_0f : arr == 1 ? p.b_0b : arr == 2 ? p.b_1f : p.b_1b;
    p.bp[arr * 2048 + rr] = src[R];
  }
  // h inits (bf16): y0 slab0 lo=h0[0]; y0 slab513 hi=h0[1]; y1f slab0=h0[2]; h1binit=h0[3]
  if (gtid < 4u * 4096) {
    unsigned dl = gtid >> 12;
    unsigned e = (gtid & 4095) * 8;
    unsigned b = e >> 9, u = e & 511;
    const float* src = p.h0 + (size_t)dl * 64 * 512 + (size_t)b * 512 + u;
    __bf16* dst;
    if (dl == 0)      dst = p.y0 + ((size_t)0 * 64 + b) * 1024 + u;
    else if (dl == 1) dst = p.y0 + ((size_t)513 * 64 + b) * 1024 + 512 + u;
    else if (dl == 2) dst = p.y1f + ((size_t)0 * 64 + b) * 512 + u;
    else              dst = p.h1binit + (size_t)b * 512 + u;
    bf16x8 v;
    #pragma unroll
    for (int j = 0; j < 8; ++j) v[j] = (__bf16)src[j];
    *(bf16x8*)dst = v;
  }

  phase_barrier(p.flags, wg, tid, 1u);

  // Fast path requires: my residue class (the 32 WGs I exchange h/flags with)
  // on ONE XCD, and the 8 classes on 8 DISTINCT XCDs (guards a broken getreg
  // that reads a constant -- which would otherwise fake "single-XCD").
  bool fast;
  {
    const unsigned* xt = p.flags + 512;
    const int r = wg & 7;
    unsigned x0 = xt[r];
    bool ok = true;
    for (int k = 1; k < 32; ++k) ok &= (xt[r + 8 * k] == x0);
    unsigned mask = 0;
    for (int rr = 0; rr < 8; ++rr) mask |= 1u << (xt[rr] & 31);
    ok &= (__popc(mask) == 8);
    fast = ok;   // identical across all members of a class
  }

  // ---------------- P1: layer0 recurrence ----------------
  // group g = wg & 7 (fwd: 0..3, bwd: 4..7; bg = g & 3); ug = wg >> 3.
  {
    const int g = wg & 7;
    const bool fwd = g < 4;
    const int bg = g & 3;
    const int ug = wg >> 3;
    const int bbase = bg * 16;
    const int uglob = ug * 16 + wv * 4;  // this wave: 4 hidden units
    const int colbase = uglob * 4;       // 16 permuted gate cols
    const __bf16* Wp = fwd ? p.Wp0f : p.Wp0b;
    bf16x8 wf[24];
    #pragma unroll
    for (int kb = 0; kb < 24; ++kb)
      wf[kb] = *(const bf16x8*)(Wp + (size_t)(colbase + colq) * 768 + kb * 32 + quad * 8);
    const float bias_col = p.bp[(fwd ? 0 : 1) * 2048 + colbase + colq];
    // per-lane c: batch row bbase+(lane>>2), unit uglob+(lane&3)
    float c = p.c0[(size_t)(fwd ? 0 : 1) * 64 * 512 +
                   (size_t)(bbase + (lane >> 2)) * 512 + uglob + (lane & 3)];
    const int dcol = fwd ? 0 : 512;
    unsigned* gfl = p.stepf + (size_t)g * 32 * 16;
    bool alive = true;
    for (int s = 0; s < 512; ++s) {
      const int t = fwd ? s : 511 - s;
      const int slabA = fwd ? t : t + 2;   // h(t-1) at slab t; h(t+1) at slab t+2
      const __bf16* aX = p.xT + ((size_t)t * 64 + bbase + colq) * 256 + quad * 8;
      bf16x8 xf[8];
      const bool pre = (wv != 0) || (s == 0);  // wave 0 defers: keeps poll's vmcnt clean
      if (pre) {
        #pragma unroll
        for (int kb = 0; kb < 8; ++kb) xf[kb] = *(const bf16x8*)(aX + kb * 32);
      }
      if (s > 0) {
        if (wv == 0 && alive) alive = group_wait32(gfl, lane, (unsigned)s);
        __syncthreads();                  // release all 4 waves
      }
      if (!pre) {                         // L1-hot: waves 1..3 already pulled it
        #pragma unroll
        for (int kb = 0; kb < 8; ++kb) xf[kb] = *(const bf16x8*)(aX + kb * 32);
      }
      // h fragments: plain cached (write-once slab; same-XCD L2-dirty hit in
      // fast path, IF first-touch in slow path)
      const __bf16* aH = p.y0 + ((size_t)slabA * 64 + bbase + colq) * 1024 + dcol + quad * 8;
      f32x4 acc = {0.f, 0.f, 0.f, 0.f};
      #pragma unroll
      for (int kb = 0; kb < 8; ++kb)
        acc = __builtin_amdgcn_mfma_f32_16x16x32_bf16(xf[kb], wf[16 + kb], acc, 0, 0, 0);
      #pragma unroll
      for (int kb = 0; kb < 16; ++kb)
        acc = __builtin_amdgcn_mfma_f32_16x16x32_bf16(*(const bf16x8*)(aH + kb * 32), wf[kb], acc, 0, 0, 0);
      // acc[r]: batch row quad*4+r, gate col colq -> LDS [batch][gate], stride 20
      #pragma unroll
      for (int r = 0; r < 4; ++r) ldsw[(quad * 4 + r) * 20 + colq] = acc[r] + bias_col;
      pointwise_store(ldsw, lane, c,
        p.y0 + ((size_t)(t + 1) * 64 + bbase + (lane >> 2)) * 1024 + dcol + uglob, fast);
      if (s < 511) {
        asm volatile("s_waitcnt vmcnt(0)" ::: "memory");  // h stores ack'd (L2 fast / IF slow)
        __syncthreads();                                  // all 4 waves drained
        if (tid == 0)                                     // single-writer flag line
          flag_store(gfl + (size_t)ug * 16, (unsigned)(s + 1), fast);
      }
    }
  }
  phase_barrier(p.flags, wg, tid, 2u);

  // ---------------- P3: layer1 fwd ((wg&7)<4) | P4: layer1 bwd single step ----------------
  if ((wg & 7) < 4) {
    const int bg = wg & 7;
    const int ug = wg >> 3;
    const int bbase = bg * 16;
    const int uglob = ug * 16 + wv * 4;
    const int colbase = uglob * 4;
    bf16x8 wf[48];                       // [hh 16 | ih 32] frags
    #pragma unroll
    for (int kb = 0; kb < 48; ++kb)
      wf[kb] = *(const bf16x8*)(p.Wp1f + (size_t)(colbase + colq) * 1536 + kb * 32 + quad * 8);
    const float bias_col = p.bp[2 * 2048 + colbase + colq];
    float c = p.c0[(size_t)2 * 64 * 512 +
                   (size_t)(bbase + (lane >> 2)) * 512 + uglob + (lane & 3)];
    unsigned* gfl = p.stepf + (size_t)(8 + bg) * 32 * 16;
    bool alive = true;
    for (int t = 0; t < 512; ++t) {
      // x = y0 slab t+1 (available since barrier 2)
      const __bf16* aX = p.y0 + ((size_t)(t + 1) * 64 + bbase + colq) * 1024 + quad * 8;
      bf16x8 xf[32];
      const bool pre = (wv != 0) || (t == 0);
      if (pre) {
        #pragma unroll
        for (int kb = 0; kb < 32; ++kb) xf[kb] = *(const bf16x8*)(aX + kb * 32);
      }
      if (t > 0) {
        if (wv == 0 && alive) alive = group_wait32(gfl, lane, (unsigned)t);
        __syncthreads();
      }
      if (!pre) {
        #pragma unroll
        for (int kb = 0; kb < 32; ++kb) xf[kb] = *(const bf16x8*)(aX + kb * 32);
      }
      // h = y1f slab t (write-once; same-XCD L2-dirty hit in fast path)
      const __bf16* aH = p.y1f + ((size_t)t * 64 + bbase + colq) * 512 + quad * 8;
      f32x4 acc = {0.f, 0.f, 0.f, 0.f};
      #pragma unroll
      for (int kb = 0; kb < 32; ++kb)
        acc = __builtin_amdgcn_mfma_f32_16x16x32_bf16(xf[kb], wf[16 + kb], acc, 0, 0, 0);
      #pragma unroll
      for (int kb = 0; kb < 16; ++kb)
        acc = __builtin_amdgcn_mfma_f32_16x16x32_bf16(*(const bf16x8*)(aH + kb * 32), wf[kb], acc, 0, 0, 0);
      #pragma unroll
      for (int r = 0; r < 4; ++r) ldsw[(quad * 4 + r) * 20 + colq] = acc[r] + bias_col;
      pointwise_store(ldsw, lane, c,
        p.y1f + ((size_t)(t + 1) * 64 + bbase + (lane >> 2)) * 512 + uglob, fast);
      if (t < 511) {
        asm volatile("s_waitcnt vmcnt(0)" ::: "memory");
        __syncthreads();
        if (tid == 0)
          flag_store(gfl + (size_t)ug * 16, (unsigned)(t + 1), fast);
      }
    }
  } else {
    const int bg = (wg & 7) - 4;
    const int ug = wg >> 3;
    const int bbase = bg * 16;
    const int uglob = ug * 16 + wv * 4;
    const int colbase = uglob * 4;
    const __bf16* aH = p.h1binit + (size_t)(bbase + colq) * 512 + quad * 8;
    const __bf16* aX = p.y0 + ((size_t)512 * 64 + bbase + colq) * 1024 + quad * 8;
    const __bf16* wrow = p.Wp1b + (size_t)(colbase + colq) * 1536;
    f32x4 acc = {0.f, 0.f, 0.f, 0.f};
    #pragma unroll
    for (int kb = 0; kb < 16; ++kb)
      acc = __builtin_amdgcn_mfma_f32_16x16x32_bf16(*(const bf16x8*)(aH + kb * 32), *(const bf16x8*)(wrow + kb * 32 + quad * 8), acc, 0, 0, 0);
    #pragma unroll
    for (int kb = 0; kb < 32; ++kb)
      acc = __builtin_amdgcn_mfma_f32_16x16x32_bf16(*(const bf16x8*)(aX + kb * 32), *(const bf16x8*)(wrow + (16 + kb) * 32 + quad * 8), acc, 0, 0, 0);
    const float bias_col = p.bp[3 * 2048 + colbase + colq];
    #pragma unroll
    for (int r = 0; r < 4; ++r) ldsw[(quad * 4 + r) * 20 + colq] = acc[r] + bias_col;
    float c = p.c0[(size_t)3 * 64 * 512 +
                   (size_t)(bbase + (lane >> 2)) * 512 + uglob + (lane & 3)];
    // consumed only after barrier 3 (FC); plain store + fence publication
    pointwise_store(ldsw, lane, c,
      p.h1bout + (size_t)(bbase + (lane >> 2)) * 512 + uglob, true);
  }
  phase_barrier(p.flags, wg, tid, 3u);

  // ---------------- FC: out[b][o] = fc_b[o] + last[b,:] . fc_w[o,:] ----------------
  if (wg < 8) {
    const int b = wg * 8 + (tid >> 5);
    const int o = (tid >> 2) & 7;
    const int ks = tid & 3;
    const int k0 = ks * 256;
    const __bf16* l1 = p.y1f + ((size_t)512 * 64 + b) * 512;   // h1f(t=511) = slab 512
    const __bf16* l2 = p.h1bout + (size_t)b * 512;             // h1b(t=511)
    const __bf16* hsrc = (ks < 2) ? (l1 + k0) : (l2 + k0 - 512);
    const float* w = p.fc_w + (size_t)o * 1024 + k0;
    float acc = 0.f;
    for (int k = 0; k < 256; ++k) acc += (float)hsrc[k] * w[k];
    acc += __shfl_down(acc, 2, 4);
    acc += __shfl_down(acc, 1, 4);
    if (ks == 0) p.out[b * 8 + o] = acc + p.fc_b[o];
  }
}

extern "C" void kernel_launch(void* const* d_in, const int* in_sizes, int n_in,
                              void* d_out, int out_size, void* d_ws, size_t ws_size,
                              hipStream_t stream) {
  char* ws = (char*)d_ws;
  Params p;
  p.input_seq = (const float*)d_in[0];
  p.h0 = (const float*)d_in[1];
  p.c0 = (const float*)d_in[2];
  p.w_ih_0f = (const float*)d_in[3];  p.w_hh_0f = (const float*)d_in[4];  p.b_0f = (const float*)d_in[5];
  p.w_ih_0b = (const float*)d_in[6];  p.w_hh_0b = (const float*)d_in[7];  p.b_0b = (const float*)d_in[8];
  p.w_ih_1f = (const float*)d_in[9];  p.w_hh_1f = (const float*)d_in[10]; p.b_1f = (const float*)d_in[11];
  p.w_ih_1b = (const float*)d_in[12]; p.w_hh_1b = (const float*)d_in[13]; p.b_1b = (const float*)d_in[14];
  p.fc_w = (const float*)d_in[15];    p.fc_b = (const float*)d_in[16];
  p.out = (float*)d_out;

  const size_t STEPF_BYTES = (size_t)12 * 32 * 64;   // 24576
  const size_t SYNC_BYTES = 4096 + STEPF_BYTES;
  size_t off = 0;
  p.flags  = (unsigned*)(ws + off); off += 4096;
  p.stepf  = (unsigned*)(ws + off); off += STEPF_BYTES;
  p.xT     = (__bf16*)(ws + off);   off += (size_t)512 * 64 * 256 * 2;
  p.Wp0f   = (__bf16*)(ws + off);   off += (size_t)2048 * 768 * 2;
  p.Wp0b   = (__bf16*)(ws + off);   off += (size_t)2048 * 768 * 2;
  p.Wp1f   = (__bf16*)(ws + off);   off += (size_t)2048 * 1536 * 2;
  p.Wp1b   = (__bf16*)(ws + off);   off += (size_t)2048 * 1536 * 2;
  p.y0     = (__bf16*)(ws + off);   off += (size_t)514 * 64 * 1024 * 2;
  p.y1f    = (__bf16*)(ws + off);   off += (size_t)513 * 64 * 512 * 2;
  p.h1binit= (__bf16*)(ws + off);   off += (size_t)64 * 512 * 2;
  p.h1bout = (__bf16*)(ws + off);   off += (size_t)64 * 512 * 2;
  p.bp     = (float*)(ws + off);    off += (size_t)4 * 2048 * 4;
  (void)ws_size; (void)in_sizes; (void)n_in; (void)out_size;

  hipMemsetAsync(d_ws, 0, SYNC_BYTES, stream);   // zero phase flags + step flags
  lstm_kernel<<<dim3(256), dim3(256), 0, stream>>>(p);
}

// Round 5
// 7739.895 us; speedup vs baseline: 5.9926x; 1.0555x over previous
//
#include <hip/hip_runtime.h>
#include <hip/hip_bf16.h>

// Bidirectional 2-layer LSTM, persistent single-kernel implementation.
// I=256, H=512, L=2, D=2, O=8, B=64, S=512.
//
// Round 12. r11 proved transport latency is NOT the bottleneck (all-IF r7 ==
// all-L2 r11 == 7.7-8.0us/hop). Attack the per-step structure instead:
//  - MFMA operand swap: mfma(W, x) instead of mfma(x, W). A/B fragment
//    layouts are lane-symmetric on gfx950 (m89), so this transposes D for
//    free: each lane now holds ALL 4 gates {i,f,g,o} of one (unit,batch) in
//    acc[0..3] -> the LDS transpose round-trip is DELETED (and its 6.3M bank
//    conflicts). Bias folds into the accumulator init (MFMA C-in).
//  - Split accumulators (3-way): dependent MFMA chain 24->8 (P1), 48->16 (P3).
//  - Per-wave step flags (128/group, own 64B line each) + NO per-step
//    __syncthreads: each wave stores its h slice, vmcnt(0), sets its flag;
//    each wave polls all 128 lines (2 per lane) independently. Removes two
//    barrier full-drains per hop and decouples the 4 waves.
//  - Uniform prefetch (wave0-defer removed); hard spin in fast mode.
// Transport kept from r11 (proven correct+equal-speed): plain h/flag stores
// in fast mode (XCD-L2), agent-scope polls, phase fences for cross-XCD
// publication, XCD-distinctness gate with r7-protocol fallback, bounded waits.

typedef __attribute__((ext_vector_type(8))) __bf16 bf16x8;
typedef __attribute__((ext_vector_type(4))) float f32x4;

struct Params {
  const float *input_seq, *h0, *c0;
  const float *w_ih_0f, *w_hh_0f, *b_0f;
  const float *w_ih_0b, *w_hh_0b, *b_0b;
  const float *w_ih_1f, *w_hh_1f, *b_1f;
  const float *w_ih_1b, *w_hh_1b, *b_1b;
  const float *fc_w, *fc_b;
  float* out;
  unsigned* flags;        // [0,256): phase slots; [512,768): xcd table
  unsigned* stepf;        // [12 groups][128 producer-waves][16 u32], 64B/line
  __bf16* xT;             // [512][64][256]  time-major bf16 input
  __bf16* Wp0f; __bf16* Wp0b;   // [2048 perm rows][768 = 512 hh | 256 ih]
  __bf16* Wp1f; __bf16* Wp1b;   // [2048 perm rows][1536 = 512 hh | 1024 ih]
  __bf16* y0;             // [514][64][1024]; slab s = t+1; slab0/513 = inits
  __bf16* y1f;            // [513][64][512]; slab t+1 = h1f(t); slab0 = init
  __bf16* h1binit;        // [64][512]
  __bf16* h1bout;         // [64][512]
  float* bp;              // [4][2048] permuted biases (0f,0b,1f,1b)
};

__device__ __forceinline__ float sigm(float x) { return 1.f / (1.f + __expf(-x)); }
__device__ __forceinline__ float tanh_fast(float x) {
  return 1.f - 2.f / (1.f + __expf(2.f * x));   // saturates correctly
}

// Phase barrier (4 uses): agent-scope; release fence publishes L2-dirty plain
// stores cross-XCD (syncthreads first drains all waves' stores to L2).
__device__ __forceinline__ void phase_barrier(unsigned* pf, int wg, int tid, unsigned phase) {
  __syncthreads();
  if (tid == 0) {
    __builtin_amdgcn_fence(__ATOMIC_RELEASE, "agent");
    __hip_atomic_store(pf + wg, phase, __ATOMIC_RELAXED, __HIP_MEMORY_SCOPE_AGENT);
  }
  bool ok;
  unsigned it = 0;
  do {
    unsigned v = __hip_atomic_load(pf + tid, __ATOMIC_RELAXED, __HIP_MEMORY_SCOPE_AGENT);
    ok = (v >= phase) || (++it > 200000u);
    if (!ok) __builtin_amdgcn_s_sleep(8);
  } while (!__syncthreads_and(ok));
  __builtin_amdgcn_fence(__ATOMIC_ACQUIRE, "agent");
}

// Every wave polls 128 producer-wave flag lines (2 per lane, 64B stride).
// Agent-scope loads (L1-bypass; served by same-XCD L2 in fast mode).
__device__ __forceinline__ bool group_wait128(const unsigned* base, int lane,
                                              unsigned need, bool fast) {
  for (unsigned it = 0;; ++it) {
    unsigned v0 = __hip_atomic_load(base + (size_t)lane * 16, __ATOMIC_RELAXED,
                                    __HIP_MEMORY_SCOPE_AGENT);
    unsigned v1 = __hip_atomic_load(base + (size_t)(lane + 64) * 16, __ATOMIC_RELAXED,
                                    __HIP_MEMORY_SCOPE_AGENT);
    bool ok = (v0 >= need) && (v1 >= need);
    if (__ballot(ok) == ~0ull) break;
    if (it > 1000000u) return false;
    if (!fast) __builtin_amdgcn_s_sleep(1);
  }
  asm volatile("" ::: "memory");   // no hoisting of h loads above the poll
  return true;
}

__device__ __forceinline__ void flag_store(unsigned* a, unsigned v, bool fast) {
  if (fast) __hip_atomic_store(a, v, __ATOMIC_RELAXED, __HIP_MEMORY_SCOPE_WORKGROUP);
  else      __hip_atomic_store(a, v, __ATOMIC_RELAXED, __HIP_MEMORY_SCOPE_AGENT);
}

// Pointwise, transposed-gate form: lane (q=lane>>4, cb=lane&15) holds gates
// {i,f,g,o} of (unit uglob+q, batch bbase+cb) in g4[0..3]. Pack the 4 units
// of one batch row (lanes cb, cb+16, cb+32, cb+48) into one u64; lanes <16
// store 8B at row (bbase+cb), col uglob.
__device__ __forceinline__ void pointwise_t(f32x4 g4, int lane, float& c,
                                            __bf16* rowptr, bool fast) {
  float cj = sigm(g4[1]) * c + sigm(g4[0]) * tanh_fast(g4[2]);
  c = cj;
  float h = sigm(g4[3]) * tanh_fast(cj);
  __bf16 hb = (__bf16)h;
  unsigned short hu; __builtin_memcpy(&hu, &hb, 2);
  unsigned v0 = (unsigned)hu | (__shfl_down((unsigned)hu, 16) << 16);
  unsigned long long pk = (unsigned long long)v0 |
                          ((unsigned long long)__shfl_down(v0, 32) << 32);
  if (lane < 16) {
    if (fast)
      __hip_atomic_store((unsigned long long*)rowptr, pk,
                         __ATOMIC_RELAXED, __HIP_MEMORY_SCOPE_WORKGROUP);
    else
      __hip_atomic_store((unsigned long long*)rowptr, pk,
                         __ATOMIC_RELAXED, __HIP_MEMORY_SCOPE_AGENT);
  }
}

__global__ __launch_bounds__(256, 2) void lstm_kernel(Params p) {
  const int tid  = threadIdx.x;
  const int wg   = blockIdx.x;
  const unsigned gtid = wg * 256 + tid;
  const int lane = tid & 63;
  const int wv   = tid >> 6;          // wave 0..3
  const int colq = lane & 15;         // fragment row/col selector
  const int quad = lane >> 4;         // k-subblock selector

  // ---------------- prologue: pack/permute/convert ----------------
  { // publish this WG's XCD id (hwreg id=20 HW_REG_XCC_ID, offset 0, size 32)
    unsigned xcd = __builtin_amdgcn_s_getreg(20 | (31 << 11));
    if (tid == 0) p.flags[512 + wg] = xcd;
  }
  { // xT[t][b][:] = bf16(input_seq[b][t][:])
    int row = gtid >> 1, half = gtid & 1;
    int t = row >> 6, b = row & 63;
    const float* src = p.input_seq + ((size_t)b * 512 + t) * 256 + half * 128;
    __bf16* dst = p.xT + (size_t)row * 256 + half * 128;
    for (int i = 0; i < 128; i += 8) {
      bf16x8 v;
      #pragma unroll
      for (int j = 0; j < 8; ++j) v[j] = (__bf16)src[i + j];
      *(bf16x8*)(dst + i) = v;
    }
  }
  // Wp0{f,b}: [2048][768]; perm row rr: u=rr>>2,g=rr&3, orig row R=g*512+u
  for (unsigned task = gtid; task < 2u * 2048 * 6; task += 65536) {
    unsigned dir = task / (2048 * 6);
    unsigned rr = (task / 6) % 2048;
    unsigned ch = task % 6;
    unsigned R = (rr & 3) * 512 + (rr >> 2);
    const float* wih = dir ? p.w_ih_0b : p.w_ih_0f;
    const float* whh = dir ? p.w_hh_0b : p.w_hh_0f;
    __bf16* dst = (dir ? p.Wp0b : p.Wp0f) + (size_t)rr * 768;
    const float* src; unsigned kd;
    if (ch < 4) { src = whh + (size_t)R * 512 + ch * 128;        kd = ch * 128; }
    else        { src = wih + (size_t)R * 256 + (ch - 4) * 128;  kd = 512 + (ch - 4) * 128; }
    for (int i = 0; i < 128; i += 8) {
      bf16x8 v;
      #pragma unroll
      for (int j = 0; j < 8; ++j) v[j] = (__bf16)src[i + j];
      *(bf16x8*)(dst + kd + i) = v;
    }
  }
  // Wp1{f,b}: [2048][1536]
  for (unsigned task = gtid; task < 2u * 2048 * 12; task += 65536) {
    unsigned dir = task / (2048 * 12);
    unsigned rr = (task / 12) % 2048;
    unsigned ch = task % 12;
    unsigned R = (rr & 3) * 512 + (rr >> 2);
    const float* wih = dir ? p.w_ih_1b : p.w_ih_1f;
    const float* whh = dir ? p.w_hh_1b : p.w_hh_1f;
    __bf16* dst = (dir ? p.Wp1b : p.Wp1f) + (size_t)rr * 1536;
    const float* src; unsigned kd;
    if (ch < 4) { src = whh + (size_t)R * 512 + ch * 128;         kd = ch * 128; }
    else        { src = wih + (size_t)R * 1024 + (ch - 4) * 128;  kd = 512 + (ch - 4) * 128; }
    for (int i = 0; i < 128; i += 8) {
      bf16x8 v;
      #pragma unroll
      for (int j = 0; j < 8; ++j) v[j] = (__bf16)src[i + j];
      *(bf16x8*)(dst + kd + i) = v;
    }
  }
  // permuted biases
  if (gtid < 4u * 2048) {
    unsigned arr = gtid >> 11, rr = gtid & 2047;
    unsigned R = (rr & 3) * 512 + (rr >> 2);
    const float* src = arr == 0 ? p.b_0f : arr == 1 ? p.b_0b : arr == 2 ? p.b_1f : p.b_1b;
    p.bp[arr * 2048 + rr] = src[R];
  }
  // h inits
  if (gtid < 4u * 4096) {
    unsigned dl = gtid >> 12;
    unsigned e = (gtid & 4095) * 8;
    unsigned b = e >> 9, u = e & 511;
    const float* src = p.h0 + (size_t)dl * 64 * 512 + (size_t)b * 512 + u;
    __bf16* dst;
    if (dl == 0)      dst = p.y0 + ((size_t)0 * 64 + b) * 1024 + u;
    else if (dl == 1) dst = p.y0 + ((size_t)513 * 64 + b) * 1024 + 512 + u;
    else if (dl == 2) dst = p.y1f + ((size_t)0 * 64 + b) * 512 + u;
    else              dst = p.h1binit + (size_t)b * 512 + u;
    bf16x8 v;
    #pragma unroll
    for (int j = 0; j < 8; ++j) v[j] = (__bf16)src[j];
    *(bf16x8*)dst = v;
  }

  phase_barrier(p.flags, wg, tid, 1u);

  // Fast path: residue class on ONE XCD + 8 classes on 8 DISTINCT XCDs.
  bool fast;
  {
    const unsigned* xt = p.flags + 512;
    const int r = wg & 7;
    unsigned x0 = xt[r];
    bool ok = true;
    for (int k = 1; k < 32; ++k) ok &= (xt[r + 8 * k] == x0);
    unsigned mask = 0;
    for (int rr = 0; rr < 8; ++rr) mask |= 1u << (xt[rr] & 31);
    ok &= (__popc(mask) == 8);
    fast = ok;
  }

  // ---------------- P1: layer0 recurrence ----------------
  {
    const int g = wg & 7;
    const bool fwd = g < 4;
    const int bg = g & 3;
    const int ug = wg >> 3;
    const int bbase = bg * 16;
    const int uglob = ug * 16 + wv * 4;  // this wave: 4 hidden units
    const int colbase = uglob * 4;       // 16 permuted gate rows
    const __bf16* Wp = fwd ? p.Wp0f : p.Wp0b;
    bf16x8 wfH[16], wfI[8];
    #pragma unroll
    for (int kb = 0; kb < 16; ++kb)
      wfH[kb] = *(const bf16x8*)(Wp + (size_t)(colbase + colq) * 768 + kb * 32 + quad * 8);
    #pragma unroll
    for (int kb = 0; kb < 8; ++kb)
      wfI[kb] = *(const bf16x8*)(Wp + (size_t)(colbase + colq) * 768 + 512 + kb * 32 + quad * 8);
    const f32x4 bias4 = *(const f32x4*)(p.bp + (fwd ? 0 : 1) * 2048 + colbase + quad * 4);
    // per-lane c: batch row bbase+(lane&15), unit uglob+(lane>>4)
    float c = p.c0[(size_t)(fwd ? 0 : 1) * 64 * 512 +
                   (size_t)(bbase + colq) * 512 + uglob + quad];
    const int dcol = fwd ? 0 : 512;
    unsigned* gfl = p.stepf + (size_t)g * 128 * 16;
    bool alive = true;
    for (int s = 0; s < 512; ++s) {
      const int t = fwd ? s : 511 - s;
      const int slabA = fwd ? t : t + 2;
      const __bf16* aX = p.xT + ((size_t)t * 64 + bbase + colq) * 256 + quad * 8;
      bf16x8 xf[8];
      #pragma unroll
      for (int kb = 0; kb < 8; ++kb) xf[kb] = *(const bf16x8*)(aX + kb * 32);
      if (s > 0 && alive) alive = group_wait128(gfl, lane, (unsigned)s, fast);
      const __bf16* aH = p.y0 + ((size_t)slabA * 64 + bbase + colq) * 1024 + dcol + quad * 8;
      f32x4 accX = bias4;
      f32x4 accH0 = {0.f, 0.f, 0.f, 0.f}, accH1 = {0.f, 0.f, 0.f, 0.f};
      #pragma unroll
      for (int kb = 0; kb < 8; ++kb)
        accX = __builtin_amdgcn_mfma_f32_16x16x32_bf16(wfI[kb], xf[kb], accX, 0, 0, 0);
      #pragma unroll
      for (int kb = 0; kb < 8; ++kb)
        accH0 = __builtin_amdgcn_mfma_f32_16x16x32_bf16(wfH[kb], *(const bf16x8*)(aH + kb * 32), accH0, 0, 0, 0);
      #pragma unroll
      for (int kb = 0; kb < 8; ++kb)
        accH1 = __builtin_amdgcn_mfma_f32_16x16x32_bf16(wfH[8 + kb], *(const bf16x8*)(aH + (8 + kb) * 32), accH1, 0, 0, 0);
      f32x4 g4 = accX + accH0 + accH1;   // lane: unit uglob+quad, batch bbase+colq
      pointwise_t(g4, lane, c,
        p.y0 + ((size_t)(t + 1) * 64 + bbase + colq) * 1024 + dcol + uglob, fast);
      if (s < 511) {
        asm volatile("s_waitcnt vmcnt(0)" ::: "memory");  // own h stores at L2/IF
        if (lane == 0)
          flag_store(gfl + (size_t)(ug * 4 + wv) * 16, (unsigned)(s + 1), fast);
      }
    }
  }
  phase_barrier(p.flags, wg, tid, 2u);

  // ---------------- P3: layer1 fwd ((wg&7)<4) | P4: layer1 bwd single step ----
  if ((wg & 7) < 4) {
    const int bg = wg & 7;
    const int ug = wg >> 3;
    const int bbase = bg * 16;
    const int uglob = ug * 16 + wv * 4;
    const int colbase = uglob * 4;
    bf16x8 wfH[16], wfX[32];
    #pragma unroll
    for (int kb = 0; kb < 16; ++kb)
      wfH[kb] = *(const bf16x8*)(p.Wp1f + (size_t)(colbase + colq) * 1536 + kb * 32 + quad * 8);
    #pragma unroll
    for (int kb = 0; kb < 32; ++kb)
      wfX[kb] = *(const bf16x8*)(p.Wp1f + (size_t)(colbase + colq) * 1536 + 512 + kb * 32 + quad * 8);
    const f32x4 bias4 = *(const f32x4*)(p.bp + 2 * 2048 + colbase + quad * 4);
    float c = p.c0[(size_t)2 * 64 * 512 +
                   (size_t)(bbase + colq) * 512 + uglob + quad];
    unsigned* gfl = p.stepf + (size_t)(8 + bg) * 128 * 16;
    bool alive = true;
    for (int t = 0; t < 512; ++t) {
      const __bf16* aX = p.y0 + ((size_t)(t + 1) * 64 + bbase + colq) * 1024 + quad * 8;
      bf16x8 xf[32];
      #pragma unroll
      for (int kb = 0; kb < 32; ++kb) xf[kb] = *(const bf16x8*)(aX + kb * 32);
      if (t > 0 && alive) alive = group_wait128(gfl, lane, (unsigned)t, fast);
      const __bf16* aH = p.y1f + ((size_t)t * 64 + bbase + colq) * 512 + quad * 8;
      f32x4 accH = bias4;
      f32x4 accX0 = {0.f, 0.f, 0.f, 0.f}, accX1 = {0.f, 0.f, 0.f, 0.f};
      #pragma unroll
      for (int kb = 0; kb < 16; ++kb)
        accH = __builtin_amdgcn_mfma_f32_16x16x32_bf16(wfH[kb], *(const bf16x8*)(aH + kb * 32), accH, 0, 0, 0);
      #pragma unroll
      for (int kb = 0; kb < 16; ++kb)
        accX0 = __builtin_amdgcn_mfma_f32_16x16x32_bf16(wfX[kb], xf[kb], accX0, 0, 0, 0);
      #pragma unroll
      for (int kb = 0; kb < 16; ++kb)
        accX1 = __builtin_amdgcn_mfma_f32_16x16x32_bf16(wfX[16 + kb], xf[16 + kb], accX1, 0, 0, 0);
      f32x4 g4 = accH + accX0 + accX1;
      pointwise_t(g4, lane, c,
        p.y1f + ((size_t)(t + 1) * 64 + bbase + colq) * 512 + uglob, fast);
      if (t < 511) {
        asm volatile("s_waitcnt vmcnt(0)" ::: "memory");
        if (lane == 0)
          flag_store(gfl + (size_t)(ug * 4 + wv) * 16, (unsigned)(t + 1), fast);
      }
    }
  } else {
    const int bg = (wg & 7) - 4;
    const int ug = wg >> 3;
    const int bbase = bg * 16;
    const int uglob = ug * 16 + wv * 4;
    const int colbase = uglob * 4;
    const __bf16* aH = p.h1binit + (size_t)(bbase + colq) * 512 + quad * 8;
    const __bf16* aX = p.y0 + ((size_t)512 * 64 + bbase + colq) * 1024 + quad * 8;
    const __bf16* wrow = p.Wp1b + (size_t)(colbase + colq) * 1536;
    const f32x4 bias4 = *(const f32x4*)(p.bp + 3 * 2048 + colbase + quad * 4);
    f32x4 accH = bias4;
    f32x4 accX0 = {0.f, 0.f, 0.f, 0.f}, accX1 = {0.f, 0.f, 0.f, 0.f};
    #pragma unroll
    for (int kb = 0; kb < 16; ++kb)
      accH = __builtin_amdgcn_mfma_f32_16x16x32_bf16(*(const bf16x8*)(wrow + kb * 32 + quad * 8),
                                                     *(const bf16x8*)(aH + kb * 32), accH, 0, 0, 0);
    #pragma unroll
    for (int kb = 0; kb < 16; ++kb)
      accX0 = __builtin_amdgcn_mfma_f32_16x16x32_bf16(*(const bf16x8*)(wrow + (16 + kb) * 32 + quad * 8),
                                                      *(const bf16x8*)(aX + kb * 32), accX0, 0, 0, 0);
    #pragma unroll
    for (int kb = 0; kb < 16; ++kb)
      accX1 = __builtin_amdgcn_mfma_f32_16x16x32_bf16(*(const bf16x8*)(wrow + (32 + kb) * 32 + quad * 8),
                                                      *(const bf16x8*)(aX + (16 + kb) * 32), accX1, 0, 0, 0);
    f32x4 g4 = accH + accX0 + accX1;
    float c = p.c0[(size_t)3 * 64 * 512 +
                   (size_t)(bbase + colq) * 512 + uglob + quad];
    pointwise_t(g4, lane, c,
      p.h1bout + (size_t)(bbase + colq) * 512 + uglob, true);
  }
  phase_barrier(p.flags, wg, tid, 3u);

  // ---------------- FC: out[b][o] = fc_b[o] + last[b,:] . fc_w[o,:] ----------
  if (wg < 8) {
    const int b = wg * 8 + (tid >> 5);
    const int o = (tid >> 2) & 7;
    const int ks = tid & 3;
    const int k0 = ks * 256;
    const __bf16* l1 = p.y1f + ((size_t)512 * 64 + b) * 512;   // h1f(t=511)
    const __bf16* l2 = p.h1bout + (size_t)b * 512;             // h1b(t=511)
    const __bf16* hsrc = (ks < 2) ? (l1 + k0) : (l2 + k0 - 512);
    const float* w = p.fc_w + (size_t)o * 1024 + k0;
    float acc = 0.f;
    for (int k = 0; k < 256; ++k) acc += (float)hsrc[k] * w[k];
    acc += __shfl_down(acc, 2, 4);
    acc += __shfl_down(acc, 1, 4);
    if (ks == 0) p.out[b * 8 + o] = acc + p.fc_b[o];
  }
}

extern "C" void kernel_launch(void* const* d_in, const int* in_sizes, int n_in,
                              void* d_out, int out_size, void* d_ws, size_t ws_size,
                              hipStream_t stream) {
  char* ws = (char*)d_ws;
  Params p;
  p.input_seq = (const float*)d_in[0];
  p.h0 = (const float*)d_in[1];
  p.c0 = (const float*)d_in[2];
  p.w_ih_0f = (const float*)d_in[3];  p.w_hh_0f = (const float*)d_in[4];  p.b_0f = (const float*)d_in[5];
  p.w_ih_0b = (const float*)d_in[6];  p.w_hh_0b = (const float*)d_in[7];  p.b_0b = (const float*)d_in[8];
  p.w_ih_1f = (const float*)d_in[9];  p.w_hh_1f = (const float*)d_in[10]; p.b_1f = (const float*)d_in[11];
  p.w_ih_1b = (const float*)d_in[12]; p.w_hh_1b = (const float*)d_in[13]; p.b_1b = (const float*)d_in[14];
  p.fc_w = (const float*)d_in[15];    p.fc_b = (const float*)d_in[16];
  p.out = (float*)d_out;

  const size_t STEPF_BYTES = (size_t)12 * 128 * 64;  // 98304
  const size_t SYNC_BYTES = 4096 + STEPF_BYTES;
  size_t off = 0;
  p.flags  = (unsigned*)(ws + off); off += 4096;
  p.stepf  = (unsigned*)(ws + off); off += STEPF_BYTES;
  p.xT     = (__bf16*)(ws + off);   off += (size_t)512 * 64 * 256 * 2;
  p.Wp0f   = (__bf16*)(ws + off);   off += (size_t)2048 * 768 * 2;
  p.Wp0b   = (__bf16*)(ws + off);   off += (size_t)2048 * 768 * 2;
  p.Wp1f   = (__bf16*)(ws + off);   off += (size_t)2048 * 1536 * 2;
  p.Wp1b   = (__bf16*)(ws + off);   off += (size_t)2048 * 1536 * 2;
  p.y0     = (__bf16*)(ws + off);   off += (size_t)514 * 64 * 1024 * 2;
  p.y1f    = (__bf16*)(ws + off);   off += (size_t)513 * 64 * 512 * 2;
  p.h1binit= (__bf16*)(ws + off);   off += (size_t)64 * 512 * 2;
  p.h1bout = (__bf16*)(ws + off);   off += (size_t)64 * 512 * 2;
  p.bp     = (float*)(ws + off);    off += (size_t)4 * 2048 * 4;
  (void)ws_size; (void)in_sizes; (void)n_in; (void)out_size;

  hipMemsetAsync(d_ws, 0, SYNC_BYTES, stream);   // zero phase flags + step flags
  lstm_kernel<<<dim3(256), dim3(256), 0, stream>>>(p);
}

// Round 6
// 6258.187 us; speedup vs baseline: 7.4114x; 1.2368x over previous
//
#include <hip/hip_runtime.h>
#include <hip/hip_bf16.h>

// Bidirectional 2-layer LSTM, persistent single-kernel implementation.
// I=256, H=512, L=2, D=2, O=8, B=64, S=512.
//
// Round 13. r11 (transport) and r12 (sync structure, LDS) both ~no-ops =>
// the invariant bottleneck is WEIGHT RESTREAMING: at VGPR_Count=128 the
// per-wave weight fragments (P1: 96 VGPRs, P3: 192 VGPRs) cannot stay
// register-resident, so every step re-pulls ~96KB/wave of weights; per XCD
// in P3 that's the whole 6MB Wp1f per step (> 4MB L2 -> partial IF), i.e.
// ~3.3GB/phase through L2/IF. Counters agree: FETCH=183MB only, hbm 49GB/s,
// hop time scope-insensitive.
// Fix (single variable vs r12): __launch_bounds__(256, 1). Occupancy today is
// already 1 WG/CU (12.4% = 4/32 waves), so the 2nd co-residency slot only
// halved the register budget. (256,1) raises the cap to 512 VGPRs -> weights
// live in registers; the K-loop's global traffic drops to x+h only.
// All r12 machinery kept: transposed-gate MFMA (no LDS), split accumulators,
// per-wave flags, no per-step __syncthreads, XCD-gated fast path with r7
// fallback, bounded waits (worst case = fast visible failure, no wedge).

typedef __attribute__((ext_vector_type(8))) __bf16 bf16x8;
typedef __attribute__((ext_vector_type(4))) float f32x4;

struct Params {
  const float *input_seq, *h0, *c0;
  const float *w_ih_0f, *w_hh_0f, *b_0f;
  const float *w_ih_0b, *w_hh_0b, *b_0b;
  const float *w_ih_1f, *w_hh_1f, *b_1f;
  const float *w_ih_1b, *w_hh_1b, *b_1b;
  const float *fc_w, *fc_b;
  float* out;
  unsigned* flags;        // [0,256): phase slots; [512,768): xcd table
  unsigned* stepf;        // [12 groups][128 producer-waves][16 u32], 64B/line
  __bf16* xT;             // [512][64][256]  time-major bf16 input
  __bf16* Wp0f; __bf16* Wp0b;   // [2048 perm rows][768 = 512 hh | 256 ih]
  __bf16* Wp1f; __bf16* Wp1b;   // [2048 perm rows][1536 = 512 hh | 1024 ih]
  __bf16* y0;             // [514][64][1024]; slab s = t+1; slab0/513 = inits
  __bf16* y1f;            // [513][64][512]; slab t+1 = h1f(t); slab0 = init
  __bf16* h1binit;        // [64][512]
  __bf16* h1bout;         // [64][512]
  float* bp;              // [4][2048] permuted biases (0f,0b,1f,1b)
};

__device__ __forceinline__ float sigm(float x) { return 1.f / (1.f + __expf(-x)); }
__device__ __forceinline__ float tanh_fast(float x) {
  return 1.f - 2.f / (1.f + __expf(2.f * x));   // saturates correctly
}

// Phase barrier (4 uses): agent-scope; release fence publishes L2-dirty plain
// stores cross-XCD (syncthreads first drains all waves' stores to L2).
__device__ __forceinline__ void phase_barrier(unsigned* pf, int wg, int tid, unsigned phase) {
  __syncthreads();
  if (tid == 0) {
    __builtin_amdgcn_fence(__ATOMIC_RELEASE, "agent");
    __hip_atomic_store(pf + wg, phase, __ATOMIC_RELAXED, __HIP_MEMORY_SCOPE_AGENT);
  }
  bool ok;
  unsigned it = 0;
  do {
    unsigned v = __hip_atomic_load(pf + tid, __ATOMIC_RELAXED, __HIP_MEMORY_SCOPE_AGENT);
    ok = (v >= phase) || (++it > 200000u);
    if (!ok) __builtin_amdgcn_s_sleep(8);
  } while (!__syncthreads_and(ok));
  __builtin_amdgcn_fence(__ATOMIC_ACQUIRE, "agent");
}

// Every wave polls 128 producer-wave flag lines (2 per lane, 64B stride).
// Agent-scope loads (L1-bypass; served by same-XCD L2 in fast mode).
__device__ __forceinline__ bool group_wait128(const unsigned* base, int lane,
                                              unsigned need, bool fast) {
  for (unsigned it = 0;; ++it) {
    unsigned v0 = __hip_atomic_load(base + (size_t)lane * 16, __ATOMIC_RELAXED,
                                    __HIP_MEMORY_SCOPE_AGENT);
    unsigned v1 = __hip_atomic_load(base + (size_t)(lane + 64) * 16, __ATOMIC_RELAXED,
                                    __HIP_MEMORY_SCOPE_AGENT);
    bool ok = (v0 >= need) && (v1 >= need);
    if (__ballot(ok) == ~0ull) break;
    if (it > 1000000u) return false;
    if (!fast) __builtin_amdgcn_s_sleep(1);
  }
  asm volatile("" ::: "memory");   // no hoisting of h loads above the poll
  return true;
}

__device__ __forceinline__ void flag_store(unsigned* a, unsigned v, bool fast) {
  if (fast) __hip_atomic_store(a, v, __ATOMIC_RELAXED, __HIP_MEMORY_SCOPE_WORKGROUP);
  else      __hip_atomic_store(a, v, __ATOMIC_RELAXED, __HIP_MEMORY_SCOPE_AGENT);
}

// Pointwise, transposed-gate form: lane (q=lane>>4, cb=lane&15) holds gates
// {i,f,g,o} of (unit uglob+q, batch bbase+cb) in g4[0..3]. Pack the 4 units
// of one batch row (lanes cb, cb+16, cb+32, cb+48) into one u64; lanes <16
// store 8B at row (bbase+cb), col uglob.
__device__ __forceinline__ void pointwise_t(f32x4 g4, int lane, float& c,
                                            __bf16* rowptr, bool fast) {
  float cj = sigm(g4[1]) * c + sigm(g4[0]) * tanh_fast(g4[2]);
  c = cj;
  float h = sigm(g4[3]) * tanh_fast(cj);
  __bf16 hb = (__bf16)h;
  unsigned short hu; __builtin_memcpy(&hu, &hb, 2);
  unsigned v0 = (unsigned)hu | (__shfl_down((unsigned)hu, 16) << 16);
  unsigned long long pk = (unsigned long long)v0 |
                          ((unsigned long long)__shfl_down(v0, 32) << 32);
  if (lane < 16) {
    if (fast)
      __hip_atomic_store((unsigned long long*)rowptr, pk,
                         __ATOMIC_RELAXED, __HIP_MEMORY_SCOPE_WORKGROUP);
    else
      __hip_atomic_store((unsigned long long*)rowptr, pk,
                         __ATOMIC_RELAXED, __HIP_MEMORY_SCOPE_AGENT);
  }
}

__global__ __launch_bounds__(256, 1) void lstm_kernel(Params p) {
  const int tid  = threadIdx.x;
  const int wg   = blockIdx.x;
  const unsigned gtid = wg * 256 + tid;
  const int lane = tid & 63;
  const int wv   = tid >> 6;          // wave 0..3
  const int colq = lane & 15;         // fragment row/col selector
  const int quad = lane >> 4;         // k-subblock selector

  // ---------------- prologue: pack/permute/convert ----------------
  { // publish this WG's XCD id (hwreg id=20 HW_REG_XCC_ID, offset 0, size 32)
    unsigned xcd = __builtin_amdgcn_s_getreg(20 | (31 << 11));
    if (tid == 0) p.flags[512 + wg] = xcd;
  }
  { // xT[t][b][:] = bf16(input_seq[b][t][:])
    int row = gtid >> 1, half = gtid & 1;
    int t = row >> 6, b = row & 63;
    const float* src = p.input_seq + ((size_t)b * 512 + t) * 256 + half * 128;
    __bf16* dst = p.xT + (size_t)row * 256 + half * 128;
    for (int i = 0; i < 128; i += 8) {
      bf16x8 v;
      #pragma unroll
      for (int j = 0; j < 8; ++j) v[j] = (__bf16)src[i + j];
      *(bf16x8*)(dst + i) = v;
    }
  }
  // Wp0{f,b}: [2048][768]; perm row rr: u=rr>>2,g=rr&3, orig row R=g*512+u
  for (unsigned task = gtid; task < 2u * 2048 * 6; task += 65536) {
    unsigned dir = task / (2048 * 6);
    unsigned rr = (task / 6) % 2048;
    unsigned ch = task % 6;
    unsigned R = (rr & 3) * 512 + (rr >> 2);
    const float* wih = dir ? p.w_ih_0b : p.w_ih_0f;
    const float* whh = dir ? p.w_hh_0b : p.w_hh_0f;
    __bf16* dst = (dir ? p.Wp0b : p.Wp0f) + (size_t)rr * 768;
    const float* src; unsigned kd;
    if (ch < 4) { src = whh + (size_t)R * 512 + ch * 128;        kd = ch * 128; }
    else        { src = wih + (size_t)R * 256 + (ch - 4) * 128;  kd = 512 + (ch - 4) * 128; }
    for (int i = 0; i < 128; i += 8) {
      bf16x8 v;
      #pragma unroll
      for (int j = 0; j < 8; ++j) v[j] = (__bf16)src[i + j];
      *(bf16x8*)(dst + kd + i) = v;
    }
  }
  // Wp1{f,b}: [2048][1536]
  for (unsigned task = gtid; task < 2u * 2048 * 12; task += 65536) {
    unsigned dir = task / (2048 * 12);
    unsigned rr = (task / 12) % 2048;
    unsigned ch = task % 12;
    unsigned R = (rr & 3) * 512 + (rr >> 2);
    const float* wih = dir ? p.w_ih_1b : p.w_ih_1f;
    const float* whh = dir ? p.w_hh_1b : p.w_hh_1f;
    __bf16* dst = (dir ? p.Wp1b : p.Wp1f) + (size_t)rr * 1536;
    const float* src; unsigned kd;
    if (ch < 4) { src = whh + (size_t)R * 512 + ch * 128;         kd = ch * 128; }
    else        { src = wih + (size_t)R * 1024 + (ch - 4) * 128;  kd = 512 + (ch - 4) * 128; }
    for (int i = 0; i < 128; i += 8) {
      bf16x8 v;
      #pragma unroll
      for (int j = 0; j < 8; ++j) v[j] = (__bf16)src[i + j];
      *(bf16x8*)(dst + kd + i) = v;
    }
  }
  // permuted biases
  if (gtid < 4u * 2048) {
    unsigned arr = gtid >> 11, rr = gtid & 2047;
    unsigned R = (rr & 3) * 512 + (rr >> 2);
    const float* src = arr == 0 ? p.b_0f : arr == 1 ? p.b_0b : arr == 2 ? p.b_1f : p.b_1b;
    p.bp[arr * 2048 + rr] = src[R];
  }
  // h inits
  if (gtid < 4u * 4096) {
    unsigned dl = gtid >> 12;
    unsigned e = (gtid & 4095) * 8;
    unsigned b = e >> 9, u = e & 511;
    const float* src = p.h0 + (size_t)dl * 64 * 512 + (size_t)b * 512 + u;
    __bf16* dst;
    if (dl == 0)      dst = p.y0 + ((size_t)0 * 64 + b) * 1024 + u;
    else if (dl == 1) dst = p.y0 + ((size_t)513 * 64 + b) * 1024 + 512 + u;
    else if (dl == 2) dst = p.y1f + ((size_t)0 * 64 + b) * 512 + u;
    else              dst = p.h1binit + (size_t)b * 512 + u;
    bf16x8 v;
    #pragma unroll
    for (int j = 0; j < 8; ++j) v[j] = (__bf16)src[j];
    *(bf16x8*)dst = v;
  }

  phase_barrier(p.flags, wg, tid, 1u);

  // Fast path: residue class on ONE XCD + 8 classes on 8 DISTINCT XCDs.
  bool fast;
  {
    const unsigned* xt = p.flags + 512;
    const int r = wg & 7;
    unsigned x0 = xt[r];
    bool ok = true;
    for (int k = 1; k < 32; ++k) ok &= (xt[r + 8 * k] == x0);
    unsigned mask = 0;
    for (int rr = 0; rr < 8; ++rr) mask |= 1u << (xt[rr] & 31);
    ok &= (__popc(mask) == 8);
    fast = ok;
  }

  // ---------------- P1: layer0 recurrence ----------------
  {
    const int g = wg & 7;
    const bool fwd = g < 4;
    const int bg = g & 3;
    const int ug = wg >> 3;
    const int bbase = bg * 16;
    const int uglob = ug * 16 + wv * 4;  // this wave: 4 hidden units
    const int colbase = uglob * 4;       // 16 permuted gate rows
    const __bf16* Wp = fwd ? p.Wp0f : p.Wp0b;
    bf16x8 wfH[16], wfI[8];
    #pragma unroll
    for (int kb = 0; kb < 16; ++kb)
      wfH[kb] = *(const bf16x8*)(Wp + (size_t)(colbase + colq) * 768 + kb * 32 + quad * 8);
    #pragma unroll
    for (int kb = 0; kb < 8; ++kb)
      wfI[kb] = *(const bf16x8*)(Wp + (size_t)(colbase + colq) * 768 + 512 + kb * 32 + quad * 8);
    const f32x4 bias4 = *(const f32x4*)(p.bp + (fwd ? 0 : 1) * 2048 + colbase + quad * 4);
    // per-lane c: batch row bbase+(lane&15), unit uglob+(lane>>4)
    float c = p.c0[(size_t)(fwd ? 0 : 1) * 64 * 512 +
                   (size_t)(bbase + colq) * 512 + uglob + quad];
    const int dcol = fwd ? 0 : 512;
    unsigned* gfl = p.stepf + (size_t)g * 128 * 16;
    bool alive = true;
    for (int s = 0; s < 512; ++s) {
      const int t = fwd ? s : 511 - s;
      const int slabA = fwd ? t : t + 2;
      const __bf16* aX = p.xT + ((size_t)t * 64 + bbase + colq) * 256 + quad * 8;
      bf16x8 xf[8];
      #pragma unroll
      for (int kb = 0; kb < 8; ++kb) xf[kb] = *(const bf16x8*)(aX + kb * 32);
      if (s > 0 && alive) alive = group_wait128(gfl, lane, (unsigned)s, fast);
      const __bf16* aH = p.y0 + ((size_t)slabA * 64 + bbase + colq) * 1024 + dcol + quad * 8;
      f32x4 accX = bias4;
      f32x4 accH0 = {0.f, 0.f, 0.f, 0.f}, accH1 = {0.f, 0.f, 0.f, 0.f};
      #pragma unroll
      for (int kb = 0; kb < 8; ++kb)
        accX = __builtin_amdgcn_mfma_f32_16x16x32_bf16(wfI[kb], xf[kb], accX, 0, 0, 0);
      #pragma unroll
      for (int kb = 0; kb < 8; ++kb)
        accH0 = __builtin_amdgcn_mfma_f32_16x16x32_bf16(wfH[kb], *(const bf16x8*)(aH + kb * 32), accH0, 0, 0, 0);
      #pragma unroll
      for (int kb = 0; kb < 8; ++kb)
        accH1 = __builtin_amdgcn_mfma_f32_16x16x32_bf16(wfH[8 + kb], *(const bf16x8*)(aH + (8 + kb) * 32), accH1, 0, 0, 0);
      f32x4 g4 = accX + accH0 + accH1;   // lane: unit uglob+quad, batch bbase+colq
      pointwise_t(g4, lane, c,
        p.y0 + ((size_t)(t + 1) * 64 + bbase + colq) * 1024 + dcol + uglob, fast);
      if (s < 511) {
        asm volatile("s_waitcnt vmcnt(0)" ::: "memory");  // own h stores at L2/IF
        if (lane == 0)
          flag_store(gfl + (size_t)(ug * 4 + wv) * 16, (unsigned)(s + 1), fast);
      }
    }
  }
  phase_barrier(p.flags, wg, tid, 2u);

  // ---------------- P3: layer1 fwd ((wg&7)<4) | P4: layer1 bwd single step ----
  if ((wg & 7) < 4) {
    const int bg = wg & 7;
    const int ug = wg >> 3;
    const int bbase = bg * 16;
    const int uglob = ug * 16 + wv * 4;
    const int colbase = uglob * 4;
    bf16x8 wfH[16], wfX[32];
    #pragma unroll
    for (int kb = 0; kb < 16; ++kb)
      wfH[kb] = *(const bf16x8*)(p.Wp1f + (size_t)(colbase + colq) * 1536 + kb * 32 + quad * 8);
    #pragma unroll
    for (int kb = 0; kb < 32; ++kb)
      wfX[kb] = *(const bf16x8*)(p.Wp1f + (size_t)(colbase + colq) * 1536 + 512 + kb * 32 + quad * 8);
    const f32x4 bias4 = *(const f32x4*)(p.bp + 2 * 2048 + colbase + quad * 4);
    float c = p.c0[(size_t)2 * 64 * 512 +
                   (size_t)(bbase + colq) * 512 + uglob + quad];
    unsigned* gfl = p.stepf + (size_t)(8 + bg) * 128 * 16;
    bool alive = true;
    for (int t = 0; t < 512; ++t) {
      const __bf16* aX = p.y0 + ((size_t)(t + 1) * 64 + bbase + colq) * 1024 + quad * 8;
      bf16x8 xf[32];
      #pragma unroll
      for (int kb = 0; kb < 32; ++kb) xf[kb] = *(const bf16x8*)(aX + kb * 32);
      if (t > 0 && alive) alive = group_wait128(gfl, lane, (unsigned)t, fast);
      const __bf16* aH = p.y1f + ((size_t)t * 64 + bbase + colq) * 512 + quad * 8;
      f32x4 accH = bias4;
      f32x4 accX0 = {0.f, 0.f, 0.f, 0.f}, accX1 = {0.f, 0.f, 0.f, 0.f};
      #pragma unroll
      for (int kb = 0; kb < 16; ++kb)
        accH = __builtin_amdgcn_mfma_f32_16x16x32_bf16(wfH[kb], *(const bf16x8*)(aH + kb * 32), accH, 0, 0, 0);
      #pragma unroll
      for (int kb = 0; kb < 16; ++kb)
        accX0 = __builtin_amdgcn_mfma_f32_16x16x32_bf16(wfX[kb], xf[kb], accX0, 0, 0, 0);
      #pragma unroll
      for (int kb = 0; kb < 16; ++kb)
        accX1 = __builtin_amdgcn_mfma_f32_16x16x32_bf16(wfX[16 + kb], xf[16 + kb], accX1, 0, 0, 0);
      f32x4 g4 = accH + accX0 + accX1;
      pointwise_t(g4, lane, c,
        p.y1f + ((size_t)(t + 1) * 64 + bbase + colq) * 512 + uglob, fast);
      if (t < 511) {
        asm volatile("s_waitcnt vmcnt(0)" ::: "memory");
        if (lane == 0)
          flag_store(gfl + (size_t)(ug * 4 + wv) * 16, (unsigned)(t + 1), fast);
      }
    }
  } else {
    const int bg = (wg & 7) - 4;
    const int ug = wg >> 3;
    const int bbase = bg * 16;
    const int uglob = ug * 16 + wv * 4;
    const int colbase = uglob * 4;
    const __bf16* aH = p.h1binit + (size_t)(bbase + colq) * 512 + quad * 8;
    const __bf16* aX = p.y0 + ((size_t)512 * 64 + bbase + colq) * 1024 + quad * 8;
    const __bf16* wrow = p.Wp1b + (size_t)(colbase + colq) * 1536;
    const f32x4 bias4 = *(const f32x4*)(p.bp + 3 * 2048 + colbase + quad * 4);
    f32x4 accH = bias4;
    f32x4 accX0 = {0.f, 0.f, 0.f, 0.f}, accX1 = {0.f, 0.f, 0.f, 0.f};
    #pragma unroll
    for (int kb = 0; kb < 16; ++kb)
      accH = __builtin_amdgcn_mfma_f32_16x16x32_bf16(*(const bf16x8*)(wrow + kb * 32 + quad * 8),
                                                     *(const bf16x8*)(aH + kb * 32), accH, 0, 0, 0);
    #pragma unroll
    for (int kb = 0; kb < 16; ++kb)
      accX0 = __builtin_amdgcn_mfma_f32_16x16x32_bf16(*(const bf16x8*)(wrow + (16 + kb) * 32 + quad * 8),
                                                      *(const bf16x8*)(aX + kb * 32), accX0, 0, 0, 0);
    #pragma unroll
    for (int kb = 0; kb < 16; ++kb)
      accX1 = __builtin_amdgcn_mfma_f32_16x16x32_bf16(*(const bf16x8*)(wrow + (32 + kb) * 32 + quad * 8),
                                                      *(const bf16x8*)(aX + (16 + kb) * 32), accX1, 0, 0, 0);
    f32x4 g4 = accH + accX0 + accX1;
    float c = p.c0[(size_t)3 * 64 * 512 +
                   (size_t)(bbase + colq) * 512 + uglob + quad];
    pointwise_t(g4, lane, c,
      p.h1bout + (size_t)(bbase + colq) * 512 + uglob, true);
  }
  phase_barrier(p.flags, wg, tid, 3u);

  // ---------------- FC: out[b][o] = fc_b[o] + last[b,:] . fc_w[o,:] ----------
  if (wg < 8) {
    const int b = wg * 8 + (tid >> 5);
    const int o = (tid >> 2) & 7;
    const int ks = tid & 3;
    const int k0 = ks * 256;
    const __bf16* l1 = p.y1f + ((size_t)512 * 64 + b) * 512;   // h1f(t=511)
    const __bf16* l2 = p.h1bout + (size_t)b * 512;             // h1b(t=511)
    const __bf16* hsrc = (ks < 2) ? (l1 + k0) : (l2 + k0 - 512);
    const float* w = p.fc_w + (size_t)o * 1024 + k0;
    float acc = 0.f;
    for (int k = 0; k < 256; ++k) acc += (float)hsrc[k] * w[k];
    acc += __shfl_down(acc, 2, 4);
    acc += __shfl_down(acc, 1, 4);
    if (ks == 0) p.out[b * 8 + o] = acc + p.fc_b[o];
  }
}

extern "C" void kernel_launch(void* const* d_in, const int* in_sizes, int n_in,
                              void* d_out, int out_size, void* d_ws, size_t ws_size,
                              hipStream_t stream) {
  char* ws = (char*)d_ws;
  Params p;
  p.input_seq = (const float*)d_in[0];
  p.h0 = (const float*)d_in[1];
  p.c0 = (const float*)d_in[2];
  p.w_ih_0f = (const float*)d_in[3];  p.w_hh_0f = (const float*)d_in[4];  p.b_0f = (const float*)d_in[5];
  p.w_ih_0b = (const float*)d_in[6];  p.w_hh_0b = (const float*)d_in[7];  p.b_0b = (const float*)d_in[8];
  p.w_ih_1f = (const float*)d_in[9];  p.w_hh_1f = (const float*)d_in[10]; p.b_1f = (const float*)d_in[11];
  p.w_ih_1b = (const float*)d_in[12]; p.w_hh_1b = (const float*)d_in[13]; p.b_1b = (const float*)d_in[14];
  p.fc_w = (const float*)d_in[15];    p.fc_b = (const float*)d_in[16];
  p.out = (float*)d_out;

  const size_t STEPF_BYTES = (size_t)12 * 128 * 64;  // 98304
  const size_t SYNC_BYTES = 4096 + STEPF_BYTES;
  size_t off = 0;
  p.flags  = (unsigned*)(ws + off); off += 4096;
  p.stepf  = (unsigned*)(ws + off); off += STEPF_BYTES;
  p.xT     = (__bf16*)(ws + off);   off += (size_t)512 * 64 * 256 * 2;
  p.Wp0f   = (__bf16*)(ws + off);   off += (size_t)2048 * 768 * 2;
  p.Wp0b   = (__bf16*)(ws + off);   off += (size_t)2048 * 768 * 2;
  p.Wp1f   = (__bf16*)(ws + off);   off += (size_t)2048 * 1536 * 2;
  p.Wp1b   = (__bf16*)(ws + off);   off += (size_t)2048 * 1536 * 2;
  p.y0     = (__bf16*)(ws + off);   off += (size_t)514 * 64 * 1024 * 2;
  p.y1f    = (__bf16*)(ws + off);   off += (size_t)513 * 64 * 512 * 2;
  p.h1binit= (__bf16*)(ws + off);   off += (size_t)64 * 512 * 2;
  p.h1bout = (__bf16*)(ws + off);   off += (size_t)64 * 512 * 2;
  p.bp     = (float*)(ws + off);    off += (size_t)4 * 2048 * 4;
  (void)ws_size; (void)in_sizes; (void)n_in; (void)out_size;

  hipMemsetAsync(d_ws, 0, SYNC_BYTES, stream);   // zero phase flags + step flags
  lstm_kernel<<<dim3(256), dim3(256), 0, stream>>>(p);
}

// Round 7
// 5838.571 us; speedup vs baseline: 7.9440x; 1.0719x over previous
//
#include <hip/hip_runtime.h>
#include <hip/hip_bf16.h>

// Bidirectional 2-layer LSTM, persistent single-kernel implementation.
// I=256, H=512, L=2, D=2, O=8, B=64, S=512.
//
// Round 14. r13 (+512-reg cap) removed P1 spills (-19%); P3 still needs ~350
// live regs and spills ~160 -> scratch reloads every step on the post-poll
// critical path. Make P3 fit WITHOUT trusting the allocator:
//  - wfX frags 0..15 -> static 64KB LDS (wave-private quarter, filled once,
//    conflict-free ds_read_b128); frags 16..31 -> registers (64 VGPR);
//    wfH[16] stays in registers. Peak live ~200 -> no spills.
//  - accX chains PRE-POLL (P1: 8 MFMA, P3: 32 MFMA): x(t) is ready before
//    h(t-1); only the 16 h-side MFMAs remain on the post-poll path.
//  - pointwise: direct per-lane 2B stores (drop the 2-shfl u64 pack).
// Transport unchanged from r13 (proven): plain h/flag stores in fast mode
// (XCD-L2), agent-scope polls, phase fences for cross-XCD publication, XCD
// gate with r7 fallback, bounded waits.

typedef __attribute__((ext_vector_type(8))) __bf16 bf16x8;
typedef __attribute__((ext_vector_type(4))) float f32x4;

struct Params {
  const float *input_seq, *h0, *c0;
  const float *w_ih_0f, *w_hh_0f, *b_0f;
  const float *w_ih_0b, *w_hh_0b, *b_0b;
  const float *w_ih_1f, *w_hh_1f, *b_1f;
  const float *w_ih_1b, *w_hh_1b, *b_1b;
  const float *fc_w, *fc_b;
  float* out;
  unsigned* flags;        // [0,256): phase slots; [512,768): xcd table
  unsigned* stepf;        // [12 groups][128 producer-waves][16 u32], 64B/line
  __bf16* xT;             // [512][64][256]  time-major bf16 input
  __bf16* Wp0f; __bf16* Wp0b;   // [2048 perm rows][768 = 512 hh | 256 ih]
  __bf16* Wp1f; __bf16* Wp1b;   // [2048 perm rows][1536 = 512 hh | 1024 ih]
  __bf16* y0;             // [514][64][1024]; slab s = t+1; slab0/513 = inits
  __bf16* y1f;            // [513][64][512]; slab t+1 = h1f(t); slab0 = init
  __bf16* h1binit;        // [64][512]
  __bf16* h1bout;         // [64][512]
  float* bp;              // [4][2048] permuted biases (0f,0b,1f,1b)
};

__device__ __forceinline__ float sigm(float x) { return 1.f / (1.f + __expf(-x)); }
__device__ __forceinline__ float tanh_fast(float x) {
  return 1.f - 2.f / (1.f + __expf(2.f * x));   // saturates correctly
}

// Phase barrier (3 uses): agent-scope; release fence publishes L2-dirty plain
// stores cross-XCD. Timeout ~200K rounds: deadlock -> clean fail, no wedge.
__device__ __forceinline__ void phase_barrier(unsigned* pf, int wg, int tid, unsigned phase) {
  __syncthreads();
  if (tid == 0) {
    __builtin_amdgcn_fence(__ATOMIC_RELEASE, "agent");
    __hip_atomic_store(pf + wg, phase, __ATOMIC_RELAXED, __HIP_MEMORY_SCOPE_AGENT);
  }
  bool ok;
  unsigned it = 0;
  do {
    unsigned v = __hip_atomic_load(pf + tid, __ATOMIC_RELAXED, __HIP_MEMORY_SCOPE_AGENT);
    ok = (v >= phase) || (++it > 200000u);
    if (!ok) __builtin_amdgcn_s_sleep(8);
  } while (!__syncthreads_and(ok));
  __builtin_amdgcn_fence(__ATOMIC_ACQUIRE, "agent");
}

// Every wave polls 128 producer-wave flag lines (2 per lane, 64B stride).
// Agent-scope loads (L1-bypass; same-XCD L2-dirty-served in fast mode).
__device__ __forceinline__ bool group_wait128(const unsigned* base, int lane,
                                              unsigned need, bool fast) {
  for (unsigned it = 0;; ++it) {
    unsigned v0 = __hip_atomic_load(base + (size_t)lane * 16, __ATOMIC_RELAXED,
                                    __HIP_MEMORY_SCOPE_AGENT);
    unsigned v1 = __hip_atomic_load(base + (size_t)(lane + 64) * 16, __ATOMIC_RELAXED,
                                    __HIP_MEMORY_SCOPE_AGENT);
    bool ok = (v0 >= need) && (v1 >= need);
    if (__ballot(ok) == ~0ull) break;
    if (it > 1000000u) return false;
    if (!fast) __builtin_amdgcn_s_sleep(1);
  }
  asm volatile("" ::: "memory");   // no hoisting of h loads above the poll
  return true;
}

__device__ __forceinline__ void flag_store(unsigned* a, unsigned v, bool fast) {
  if (fast) __hip_atomic_store(a, v, __ATOMIC_RELAXED, __HIP_MEMORY_SCOPE_WORKGROUP);
  else      __hip_atomic_store(a, v, __ATOMIC_RELAXED, __HIP_MEMORY_SCOPE_AGENT);
}

// Pointwise, transposed-gate form, direct store: lane (q=lane>>4, cb=lane&15)
// holds gates {i,f,g,o} of (unit uglob+q, batch bbase+cb) in g4[0..3]; each
// lane stores its own 2B bf16 h (coalescer merges 4 lanes/row -> 8B lines).
__device__ __forceinline__ void pointwise_t2(f32x4 g4, float& c,
                                             __bf16* eptr, bool fast) {
  float cj = sigm(g4[1]) * c + sigm(g4[0]) * tanh_fast(g4[2]);
  c = cj;
  float h = sigm(g4[3]) * tanh_fast(cj);
  __bf16 hb = (__bf16)h;
  unsigned short hu; __builtin_memcpy(&hu, &hb, 2);
  if (fast)
    __hip_atomic_store((unsigned short*)eptr, hu,
                       __ATOMIC_RELAXED, __HIP_MEMORY_SCOPE_WORKGROUP);
  else
    __hip_atomic_store((unsigned short*)eptr, hu,
                       __ATOMIC_RELAXED, __HIP_MEMORY_SCOPE_AGENT);
}

__global__ __launch_bounds__(256, 1) void lstm_kernel(Params p) {
  const int tid  = threadIdx.x;
  const int wg   = blockIdx.x;
  const unsigned gtid = wg * 256 + tid;
  const int lane = tid & 63;
  const int wv   = tid >> 6;          // wave 0..3
  const int colq = lane & 15;         // fragment row/col selector
  const int quad = lane >> 4;         // k-subblock selector

  // 64KB static LDS: P3 wfX frags 0..15, wave-private quarter each.
  // Layout: bf16x8 at ((wv*16 + kb)*64 + lane)*8 (16B/lane, 1KB per kb-block).
  __shared__ __bf16 wlds[32768];

  // ---------------- prologue: pack/permute/convert ----------------
  { // publish this WG's XCD id (hwreg id=20 HW_REG_XCC_ID, offset 0, size 32)
    unsigned xcd = __builtin_amdgcn_s_getreg(20 | (31 << 11));
    if (tid == 0) p.flags[512 + wg] = xcd;
  }
  { // xT[t][b][:] = bf16(input_seq[b][t][:])
    int row = gtid >> 1, half = gtid & 1;
    int t = row >> 6, b = row & 63;
    const float* src = p.input_seq + ((size_t)b * 512 + t) * 256 + half * 128;
    __bf16* dst = p.xT + (size_t)row * 256 + half * 128;
    for (int i = 0; i < 128; i += 8) {
      bf16x8 v;
      #pragma unroll
      for (int j = 0; j < 8; ++j) v[j] = (__bf16)src[i + j];
      *(bf16x8*)(dst + i) = v;
    }
  }
  // Wp0{f,b}: [2048][768]; perm row rr: u=rr>>2,g=rr&3, orig row R=g*512+u
  for (unsigned task = gtid; task < 2u * 2048 * 6; task += 65536) {
    unsigned dir = task / (2048 * 6);
    unsigned rr = (task / 6) % 2048;
    unsigned ch = task % 6;
    unsigned R = (rr & 3) * 512 + (rr >> 2);
    const float* wih = dir ? p.w_ih_0b : p.w_ih_0f;
    const float* whh = dir ? p.w_hh_0b : p.w_hh_0f;
    __bf16* dst = (dir ? p.Wp0b : p.Wp0f) + (size_t)rr * 768;
    const float* src; unsigned kd;
    if (ch < 4) { src = whh + (size_t)R * 512 + ch * 128;        kd = ch * 128; }
    else        { src = wih + (size_t)R * 256 + (ch - 4) * 128;  kd = 512 + (ch - 4) * 128; }
    for (int i = 0; i < 128; i += 8) {
      bf16x8 v;
      #pragma unroll
      for (int j = 0; j < 8; ++j) v[j] = (__bf16)src[i + j];
      *(bf16x8*)(dst + kd + i) = v;
    }
  }
  // Wp1{f,b}: [2048][1536]
  for (unsigned task = gtid; task < 2u * 2048 * 12; task += 65536) {
    unsigned dir = task / (2048 * 12);
    unsigned rr = (task / 12) % 2048;
    unsigned ch = task % 12;
    unsigned R = (rr & 3) * 512 + (rr >> 2);
    const float* wih = dir ? p.w_ih_1b : p.w_ih_1f;
    const float* whh = dir ? p.w_hh_1b : p.w_hh_1f;
    __bf16* dst = (dir ? p.Wp1b : p.Wp1f) + (size_t)rr * 1536;
    const float* src; unsigned kd;
    if (ch < 4) { src = whh + (size_t)R * 512 + ch * 128;         kd = ch * 128; }
    else        { src = wih + (size_t)R * 1024 + (ch - 4) * 128;  kd = 512 + (ch - 4) * 128; }
    for (int i = 0; i < 128; i += 8) {
      bf16x8 v;
      #pragma unroll
      for (int j = 0; j < 8; ++j) v[j] = (__bf16)src[i + j];
      *(bf16x8*)(dst + kd + i) = v;
    }
  }
  // permuted biases
  if (gtid < 4u * 2048) {
    unsigned arr = gtid >> 11, rr = gtid & 2047;
    unsigned R = (rr & 3) * 512 + (rr >> 2);
    const float* src = arr == 0 ? p.b_0f : arr == 1 ? p.b_0b : arr == 2 ? p.b_1f : p.b_1b;
    p.bp[arr * 2048 + rr] = src[R];
  }
  // h inits
  if (gtid < 4u * 4096) {
    unsigned dl = gtid >> 12;
    unsigned e = (gtid & 4095) * 8;
    unsigned b = e >> 9, u = e & 511;
    const float* src = p.h0 + (size_t)dl * 64 * 512 + (size_t)b * 512 + u;
    __bf16* dst;
    if (dl == 0)      dst = p.y0 + ((size_t)0 * 64 + b) * 1024 + u;
    else if (dl == 1) dst = p.y0 + ((size_t)513 * 64 + b) * 1024 + 512 + u;
    else if (dl == 2) dst = p.y1f + ((size_t)0 * 64 + b) * 512 + u;
    else              dst = p.h1binit + (size_t)b * 512 + u;
    bf16x8 v;
    #pragma unroll
    for (int j = 0; j < 8; ++j) v[j] = (__bf16)src[j];
    *(bf16x8*)dst = v;
  }

  phase_barrier(p.flags, wg, tid, 1u);

  // Fast path: residue class on ONE XCD + 8 classes on 8 DISTINCT XCDs.
  bool fast;
  {
    const unsigned* xt = p.flags + 512;
    const int r = wg & 7;
    unsigned x0 = xt[r];
    bool ok = true;
    for (int k = 1; k < 32; ++k) ok &= (xt[r + 8 * k] == x0);
    unsigned mask = 0;
    for (int rr = 0; rr < 8; ++rr) mask |= 1u << (xt[rr] & 31);
    ok &= (__popc(mask) == 8);
    fast = ok;
  }

  // ---------------- P1: layer0 recurrence ----------------
  {
    const int g = wg & 7;
    const bool fwd = g < 4;
    const int bg = g & 3;
    const int ug = wg >> 3;
    const int bbase = bg * 16;
    const int uglob = ug * 16 + wv * 4;  // this wave: 4 hidden units
    const int colbase = uglob * 4;       // 16 permuted gate rows
    const __bf16* Wp = fwd ? p.Wp0f : p.Wp0b;
    bf16x8 wfH[16], wfI[8];
    #pragma unroll
    for (int kb = 0; kb < 16; ++kb)
      wfH[kb] = *(const bf16x8*)(Wp + (size_t)(colbase + colq) * 768 + kb * 32 + quad * 8);
    #pragma unroll
    for (int kb = 0; kb < 8; ++kb)
      wfI[kb] = *(const bf16x8*)(Wp + (size_t)(colbase + colq) * 768 + 512 + kb * 32 + quad * 8);
    const f32x4 bias4 = *(const f32x4*)(p.bp + (fwd ? 0 : 1) * 2048 + colbase + quad * 4);
    float c = p.c0[(size_t)(fwd ? 0 : 1) * 64 * 512 +
                   (size_t)(bbase + colq) * 512 + uglob + quad];
    const int dcol = fwd ? 0 : 512;
    unsigned* gfl = p.stepf + (size_t)g * 128 * 16;
    bool alive = true;
    for (int s = 0; s < 512; ++s) {
      const int t = fwd ? s : 511 - s;
      const int slabA = fwd ? t : t + 2;
      const __bf16* aX = p.xT + ((size_t)t * 64 + bbase + colq) * 256 + quad * 8;
      // pre-poll: x-side gates (x is static input)
      f32x4 accX = bias4;
      #pragma unroll
      for (int kb = 0; kb < 8; ++kb) {
        bf16x8 xv = *(const bf16x8*)(aX + kb * 32);
        accX = __builtin_amdgcn_mfma_f32_16x16x32_bf16(wfI[kb], xv, accX, 0, 0, 0);
      }
      if (s > 0 && alive) alive = group_wait128(gfl, lane, (unsigned)s, fast);
      // post-poll: h-side gates (two depth-8 chains)
      const __bf16* aH = p.y0 + ((size_t)slabA * 64 + bbase + colq) * 1024 + dcol + quad * 8;
      f32x4 accH0 = {0.f, 0.f, 0.f, 0.f}, accH1 = {0.f, 0.f, 0.f, 0.f};
      #pragma unroll
      for (int kb = 0; kb < 8; ++kb)
        accH0 = __builtin_amdgcn_mfma_f32_16x16x32_bf16(wfH[kb], *(const bf16x8*)(aH + kb * 32), accH0, 0, 0, 0);
      #pragma unroll
      for (int kb = 0; kb < 8; ++kb)
        accH1 = __builtin_amdgcn_mfma_f32_16x16x32_bf16(wfH[8 + kb], *(const bf16x8*)(aH + (8 + kb) * 32), accH1, 0, 0, 0);
      f32x4 g4 = accX + accH0 + accH1;
      pointwise_t2(g4, c,
        p.y0 + ((size_t)(t + 1) * 64 + bbase + colq) * 1024 + dcol + uglob + quad, fast);
      if (s < 511) {
        asm volatile("s_waitcnt vmcnt(0)" ::: "memory");  // own h stores at L2/IF
        if (lane == 0)
          flag_store(gfl + (size_t)(ug * 4 + wv) * 16, (unsigned)(s + 1), fast);
      }
    }
  }
  phase_barrier(p.flags, wg, tid, 2u);

  // ---------------- P3: layer1 fwd ((wg&7)<4) | P4: layer1 bwd single step ----
  if ((wg & 7) < 4) {
    const int bg = wg & 7;
    const int ug = wg >> 3;
    const int bbase = bg * 16;
    const int uglob = ug * 16 + wv * 4;
    const int colbase = uglob * 4;
    // weights: wfH[16] regs; wfX frags 0..15 -> LDS; frags 16..31 -> regs
    bf16x8 wfH[16], wfX2[16];
    #pragma unroll
    for (int kb = 0; kb < 16; ++kb)
      wfH[kb] = *(const bf16x8*)(p.Wp1f + (size_t)(colbase + colq) * 1536 + kb * 32 + quad * 8);
    {
      const __bf16* wsrc = p.Wp1f + (size_t)(colbase + colq) * 1536 + 512;
      #pragma unroll
      for (int kb = 0; kb < 16; ++kb) {
        bf16x8 w = *(const bf16x8*)(wsrc + kb * 32 + quad * 8);
        *(bf16x8*)(wlds + ((size_t)(wv * 16 + kb) * 64 + lane) * 8) = w;
      }
      #pragma unroll
      for (int kb = 0; kb < 16; ++kb)
        wfX2[kb] = *(const bf16x8*)(wsrc + (16 + kb) * 32 + quad * 8);
    }
    const f32x4 bias4 = *(const f32x4*)(p.bp + 2 * 2048 + colbase + quad * 4);
    float c = p.c0[(size_t)2 * 64 * 512 +
                   (size_t)(bbase + colq) * 512 + uglob + quad];
    unsigned* gfl = p.stepf + (size_t)(8 + bg) * 128 * 16;
    bool alive = true;
    for (int t = 0; t < 512; ++t) {
      const __bf16* aX = p.y0 + ((size_t)(t + 1) * 64 + bbase + colq) * 1024 + quad * 8;
      // pre-poll: x-side gates (y0 slab t+1 published at phase 2)
      f32x4 accX0 = bias4, accX1 = {0.f, 0.f, 0.f, 0.f};
      #pragma unroll
      for (int kb = 0; kb < 16; ++kb) {
        bf16x8 xv = *(const bf16x8*)(aX + kb * 32);
        bf16x8 wx = *(const bf16x8*)(wlds + ((size_t)(wv * 16 + kb) * 64 + lane) * 8);
        accX0 = __builtin_amdgcn_mfma_f32_16x16x32_bf16(wx, xv, accX0, 0, 0, 0);
      }
      #pragma unroll
      for (int kb = 0; kb < 16; ++kb) {
        bf16x8 xv = *(const bf16x8*)(aX + (16 + kb) * 32);
        accX1 = __builtin_amdgcn_mfma_f32_16x16x32_bf16(wfX2[kb], xv, accX1, 0, 0, 0);
      }
      if (t > 0 && alive) alive = group_wait128(gfl, lane, (unsigned)t, fast);
      // post-poll: h-side gates (two depth-8 chains)
      const __bf16* aH = p.y1f + ((size_t)t * 64 + bbase + colq) * 512 + quad * 8;
      f32x4 accH0 = {0.f, 0.f, 0.f, 0.f}, accH1 = {0.f, 0.f, 0.f, 0.f};
      #pragma unroll
      for (int kb = 0; kb < 8; ++kb)
        accH0 = __builtin_amdgcn_mfma_f32_16x16x32_bf16(wfH[kb], *(const bf16x8*)(aH + kb * 32), accH0, 0, 0, 0);
      #pragma unroll
      for (int kb = 0; kb < 8; ++kb)
        accH1 = __builtin_amdgcn_mfma_f32_16x16x32_bf16(wfH[8 + kb], *(const bf16x8*)(aH + (8 + kb) * 32), accH1, 0, 0, 0);
      f32x4 g4 = accX0 + accX1 + accH0 + accH1;
      pointwise_t2(g4, c,
        p.y1f + ((size_t)(t + 1) * 64 + bbase + colq) * 512 + uglob + quad, fast);
      if (t < 511) {
        asm volatile("s_waitcnt vmcnt(0)" ::: "memory");
        if (lane == 0)
          flag_store(gfl + (size_t)(ug * 4 + wv) * 16, (unsigned)(t + 1), fast);
      }
    }
  } else {
    const int bg = (wg & 7) - 4;
    const int ug = wg >> 3;
    const int bbase = bg * 16;
    const int uglob = ug * 16 + wv * 4;
    const int colbase = uglob * 4;
    const __bf16* aH = p.h1binit + (size_t)(bbase + colq) * 512 + quad * 8;
    const __bf16* aX = p.y0 + ((size_t)512 * 64 + bbase + colq) * 1024 + quad * 8;
    const __bf16* wrow = p.Wp1b + (size_t)(colbase + colq) * 1536;
    const f32x4 bias4 = *(const f32x4*)(p.bp + 3 * 2048 + colbase + quad * 4);
    f32x4 accH = bias4;
    f32x4 accX0 = {0.f, 0.f, 0.f, 0.f}, accX1 = {0.f, 0.f, 0.f, 0.f};
    #pragma unroll
    for (int kb = 0; kb < 16; ++kb)
      accH = __builtin_amdgcn_mfma_f32_16x16x32_bf16(*(const bf16x8*)(wrow + kb * 32 + quad * 8),
                                                     *(const bf16x8*)(aH + kb * 32), accH, 0, 0, 0);
    #pragma unroll
    for (int kb = 0; kb < 16; ++kb)
      accX0 = __builtin_amdgcn_mfma_f32_16x16x32_bf16(*(const bf16x8*)(wrow + (16 + kb) * 32 + quad * 8),
                                                      *(const bf16x8*)(aX + kb * 32), accX0, 0, 0, 0);
    #pragma unroll
    for (int kb = 0; kb < 16; ++kb)
      accX1 = __builtin_amdgcn_mfma_f32_16x16x32_bf16(*(const bf16x8*)(wrow + (32 + kb) * 32 + quad * 8),
                                                      *(const bf16x8*)(aX + (16 + kb) * 32), accX1, 0, 0, 0);
    f32x4 g4 = accH + accX0 + accX1;
    float c = p.c0[(size_t)3 * 64 * 512 +
                   (size_t)(bbase + colq) * 512 + uglob + quad];
    pointwise_t2(g4, c,
      p.h1bout + (size_t)(bbase + colq) * 512 + uglob + quad, true);
  }
  phase_barrier(p.flags, wg, tid, 3u);

  // ---------------- FC: out[b][o] = fc_b[o] + last[b,:] . fc_w[o,:] ----------
  if (wg < 8) {
    const int b = wg * 8 + (tid >> 5);
    const int o = (tid >> 2) & 7;
    const int ks = tid & 3;
    const int k0 = ks * 256;
    const __bf16* l1 = p.y1f + ((size_t)512 * 64 + b) * 512;   // h1f(t=511)
    const __bf16* l2 = p.h1bout + (size_t)b * 512;             // h1b(t=511)
    const __bf16* hsrc = (ks < 2) ? (l1 + k0) : (l2 + k0 - 512);
    const float* w = p.fc_w + (size_t)o * 1024 + k0;
    float acc = 0.f;
    for (int k = 0; k < 256; ++k) acc += (float)hsrc[k] * w[k];
    acc += __shfl_down(acc, 2, 4);
    acc += __shfl_down(acc, 1, 4);
    if (ks == 0) p.out[b * 8 + o] = acc + p.fc_b[o];
  }
}

extern "C" void kernel_launch(void* const* d_in, const int* in_sizes, int n_in,
                              void* d_out, int out_size, void* d_ws, size_t ws_size,
                              hipStream_t stream) {
  char* ws = (char*)d_ws;
  Params p;
  p.input_seq = (const float*)d_in[0];
  p.h0 = (const float*)d_in[1];
  p.c0 = (const float*)d_in[2];
  p.w_ih_0f = (const float*)d_in[3];  p.w_hh_0f = (const float*)d_in[4];  p.b_0f = (const float*)d_in[5];
  p.w_ih_0b = (const float*)d_in[6];  p.w_hh_0b = (const float*)d_in[7];  p.b_0b = (const float*)d_in[8];
  p.w_ih_1f = (const float*)d_in[9];  p.w_hh_1f = (const float*)d_in[10]; p.b_1f = (const float*)d_in[11];
  p.w_ih_1b = (const float*)d_in[12]; p.w_hh_1b = (const float*)d_in[13]; p.b_1b = (const float*)d_in[14];
  p.fc_w = (const float*)d_in[15];    p.fc_b = (const float*)d_in[16];
  p.out = (float*)d_out;

  const size_t STEPF_BYTES = (size_t)12 * 128 * 64;  // 98304
  const size_t SYNC_BYTES = 4096 + STEPF_BYTES;
  size_t off = 0;
  p.flags  = (unsigned*)(ws + off); off += 4096;
  p.stepf  = (unsigned*)(ws + off); off += STEPF_BYTES;
  p.xT     = (__bf16*)(ws + off);   off += (size_t)512 * 64 * 256 * 2;
  p.Wp0f   = (__bf16*)(ws + off);   off += (size_t)2048 * 768 * 2;
  p.Wp0b   = (__bf16*)(ws + off);   off += (size_t)2048 * 768 * 2;
  p.Wp1f   = (__bf16*)(ws + off);   off += (size_t)2048 * 1536 * 2;
  p.Wp1b   = (__bf16*)(ws + off);   off += (size_t)2048 * 1536 * 2;
  p.y0     = (__bf16*)(ws + off);   off += (size_t)514 * 64 * 1024 * 2;
  p.y1f    = (__bf16*)(ws + off);   off += (size_t)513 * 64 * 512 * 2;
  p.h1binit= (__bf16*)(ws + off);   off += (size_t)64 * 512 * 2;
  p.h1bout = (__bf16*)(ws + off);   off += (size_t)64 * 512 * 2;
  p.bp     = (float*)(ws + off);    off += (size_t)4 * 2048 * 4;
  (void)ws_size; (void)in_sizes; (void)n_in; (void)out_size;

  hipMemsetAsync(d_ws, 0, SYNC_BYTES, stream);   // zero phase flags + step flags
  lstm_kernel<<<dim3(256), dim3(256), 0, stream>>>(p);
}

// Round 8
// 5509.883 us; speedup vs baseline: 8.4179x; 1.0597x over previous
//
#include <hip/hip_runtime.h>
#include <hip/hip_bf16.h>

// Bidirectional 2-layer LSTM, persistent single-kernel implementation.
// I=256, H=512, L=2, D=2, O=8, B=64, S=512.
//
// Round 15. r14's VGPR_Count=116 (< the 128 regs wfH+wfX2 alone need) proves
// the allocator REMATERIALIZES loop-invariant weight loads from L2 every
// step instead of keeping them resident -- the per-step L2/IF weight
// restream is the invariant ~5.6us/hop cost (r13/r14 gains track exactly
// with how many fragments happened to stay resident).
// Fix: pin weight fragments with opaque empty asm ("+v") after the pre-loop
// loads -- non-rematerializable => must stay in registers (cap 512 at
// (256,1), live ~200, no spill pressure).
//  - P1: pin wfH[16]+wfI[8] (96 regs).
//  - P3: pin wfH[16]+wfX2[16] (128 regs); other 16 x-frags stay in LDS (r14).
//  - Post-poll h-side MFMA chains split 2->4 accumulators (depth 8->4).
// Everything else identical to r14: transposed-gate MFMA, pre-poll x-side
// chains, per-wave flags, no per-step __syncthreads, plain fast-mode stores
// (XCD-L2), agent-scope polls, phase fences, XCD gate + r7 fallback, bounded
// waits.

typedef __attribute__((ext_vector_type(8))) __bf16 bf16x8;
typedef __attribute__((ext_vector_type(4))) float f32x4;

struct Params {
  const float *input_seq, *h0, *c0;
  const float *w_ih_0f, *w_hh_0f, *b_0f;
  const float *w_ih_0b, *w_hh_0b, *b_0b;
  const float *w_ih_1f, *w_hh_1f, *b_1f;
  const float *w_ih_1b, *w_hh_1b, *b_1b;
  const float *fc_w, *fc_b;
  float* out;
  unsigned* flags;        // [0,256): phase slots; [512,768): xcd table
  unsigned* stepf;        // [12 groups][128 producer-waves][16 u32], 64B/line
  __bf16* xT;             // [512][64][256]  time-major bf16 input
  __bf16* Wp0f; __bf16* Wp0b;   // [2048 perm rows][768 = 512 hh | 256 ih]
  __bf16* Wp1f; __bf16* Wp1b;   // [2048 perm rows][1536 = 512 hh | 1024 ih]
  __bf16* y0;             // [514][64][1024]; slab s = t+1; slab0/513 = inits
  __bf16* y1f;            // [513][64][512]; slab t+1 = h1f(t); slab0 = init
  __bf16* h1binit;        // [64][512]
  __bf16* h1bout;         // [64][512]
  float* bp;              // [4][2048] permuted biases (0f,0b,1f,1b)
};

__device__ __forceinline__ float sigm(float x) { return 1.f / (1.f + __expf(-x)); }
__device__ __forceinline__ float tanh_fast(float x) {
  return 1.f - 2.f / (1.f + __expf(2.f * x));   // saturates correctly
}
// Opaque pin: value becomes asm-defined => non-rematerializable, must stay
// register-resident across the loop (no spill pressure at the 512-reg cap).
__device__ __forceinline__ void pin(bf16x8& v) { asm volatile("" : "+v"(v)); }

// Phase barrier (3 uses): agent-scope; release fence publishes L2-dirty plain
// stores cross-XCD. Timeout ~200K rounds: deadlock -> clean fail, no wedge.
__device__ __forceinline__ void phase_barrier(unsigned* pf, int wg, int tid, unsigned phase) {
  __syncthreads();
  if (tid == 0) {
    __builtin_amdgcn_fence(__ATOMIC_RELEASE, "agent");
    __hip_atomic_store(pf + wg, phase, __ATOMIC_RELAXED, __HIP_MEMORY_SCOPE_AGENT);
  }
  bool ok;
  unsigned it = 0;
  do {
    unsigned v = __hip_atomic_load(pf + tid, __ATOMIC_RELAXED, __HIP_MEMORY_SCOPE_AGENT);
    ok = (v >= phase) || (++it > 200000u);
    if (!ok) __builtin_amdgcn_s_sleep(8);
  } while (!__syncthreads_and(ok));
  __builtin_amdgcn_fence(__ATOMIC_ACQUIRE, "agent");
}

// Every wave polls 128 producer-wave flag lines (2 per lane, 64B stride).
// Agent-scope loads (L1-bypass; same-XCD L2-dirty-served in fast mode).
__device__ __forceinline__ bool group_wait128(const unsigned* base, int lane,
                                              unsigned need, bool fast) {
  for (unsigned it = 0;; ++it) {
    unsigned v0 = __hip_atomic_load(base + (size_t)lane * 16, __ATOMIC_RELAXED,
                                    __HIP_MEMORY_SCOPE_AGENT);
    unsigned v1 = __hip_atomic_load(base + (size_t)(lane + 64) * 16, __ATOMIC_RELAXED,
                                    __HIP_MEMORY_SCOPE_AGENT);
    bool ok = (v0 >= need) && (v1 >= need);
    if (__ballot(ok) == ~0ull) break;
    if (it > 1000000u) return false;
    if (!fast) __builtin_amdgcn_s_sleep(1);
  }
  asm volatile("" ::: "memory");   // no hoisting of h loads above the poll
  return true;
}

__device__ __forceinline__ void flag_store(unsigned* a, unsigned v, bool fast) {
  if (fast) __hip_atomic_store(a, v, __ATOMIC_RELAXED, __HIP_MEMORY_SCOPE_WORKGROUP);
  else      __hip_atomic_store(a, v, __ATOMIC_RELAXED, __HIP_MEMORY_SCOPE_AGENT);
}

// Pointwise, transposed-gate form, direct store: lane (q=lane>>4, cb=lane&15)
// holds gates {i,f,g,o} of (unit uglob+q, batch bbase+cb) in g4[0..3]; each
// lane stores its own 2B bf16 h.
__device__ __forceinline__ void pointwise_t2(f32x4 g4, float& c,
                                             __bf16* eptr, bool fast) {
  float cj = sigm(g4[1]) * c + sigm(g4[0]) * tanh_fast(g4[2]);
  c = cj;
  float h = sigm(g4[3]) * tanh_fast(cj);
  __bf16 hb = (__bf16)h;
  unsigned short hu; __builtin_memcpy(&hu, &hb, 2);
  if (fast)
    __hip_atomic_store((unsigned short*)eptr, hu,
                       __ATOMIC_RELAXED, __HIP_MEMORY_SCOPE_WORKGROUP);
  else
    __hip_atomic_store((unsigned short*)eptr, hu,
                       __ATOMIC_RELAXED, __HIP_MEMORY_SCOPE_AGENT);
}

__global__ __launch_bounds__(256, 1) void lstm_kernel(Params p) {
  const int tid  = threadIdx.x;
  const int wg   = blockIdx.x;
  const unsigned gtid = wg * 256 + tid;
  const int lane = tid & 63;
  const int wv   = tid >> 6;          // wave 0..3
  const int colq = lane & 15;         // fragment row/col selector
  const int quad = lane >> 4;         // k-subblock selector

  // 64KB static LDS: P3 wfX frags 0..15, wave-private quarter each.
  __shared__ __bf16 wlds[32768];

  // ---------------- prologue: pack/permute/convert ----------------
  { // publish this WG's XCD id (hwreg id=20 HW_REG_XCC_ID, offset 0, size 32)
    unsigned xcd = __builtin_amdgcn_s_getreg(20 | (31 << 11));
    if (tid == 0) p.flags[512 + wg] = xcd;
  }
  { // xT[t][b][:] = bf16(input_seq[b][t][:])
    int row = gtid >> 1, half = gtid & 1;
    int t = row >> 6, b = row & 63;
    const float* src = p.input_seq + ((size_t)b * 512 + t) * 256 + half * 128;
    __bf16* dst = p.xT + (size_t)row * 256 + half * 128;
    for (int i = 0; i < 128; i += 8) {
      bf16x8 v;
      #pragma unroll
      for (int j = 0; j < 8; ++j) v[j] = (__bf16)src[i + j];
      *(bf16x8*)(dst + i) = v;
    }
  }
  // Wp0{f,b}: [2048][768]; perm row rr: u=rr>>2,g=rr&3, orig row R=g*512+u
  for (unsigned task = gtid; task < 2u * 2048 * 6; task += 65536) {
    unsigned dir = task / (2048 * 6);
    unsigned rr = (task / 6) % 2048;
    unsigned ch = task % 6;
    unsigned R = (rr & 3) * 512 + (rr >> 2);
    const float* wih = dir ? p.w_ih_0b : p.w_ih_0f;
    const float* whh = dir ? p.w_hh_0b : p.w_hh_0f;
    __bf16* dst = (dir ? p.Wp0b : p.Wp0f) + (size_t)rr * 768;
    const float* src; unsigned kd;
    if (ch < 4) { src = whh + (size_t)R * 512 + ch * 128;        kd = ch * 128; }
    else        { src = wih + (size_t)R * 256 + (ch - 4) * 128;  kd = 512 + (ch - 4) * 128; }
    for (int i = 0; i < 128; i += 8) {
      bf16x8 v;
      #pragma unroll
      for (int j = 0; j < 8; ++j) v[j] = (__bf16)src[i + j];
      *(bf16x8*)(dst + kd + i) = v;
    }
  }
  // Wp1{f,b}: [2048][1536]
  for (unsigned task = gtid; task < 2u * 2048 * 12; task += 65536) {
    unsigned dir = task / (2048 * 12);
    unsigned rr = (task / 12) % 2048;
    unsigned ch = task % 12;
    unsigned R = (rr & 3) * 512 + (rr >> 2);
    const float* wih = dir ? p.w_ih_1b : p.w_ih_1f;
    const float* whh = dir ? p.w_hh_1b : p.w_hh_1f;
    __bf16* dst = (dir ? p.Wp1b : p.Wp1f) + (size_t)rr * 1536;
    const float* src; unsigned kd;
    if (ch < 4) { src = whh + (size_t)R * 512 + ch * 128;         kd = ch * 128; }
    else        { src = wih + (size_t)R * 1024 + (ch - 4) * 128;  kd = 512 + (ch - 4) * 128; }
    for (int i = 0; i < 128; i += 8) {
      bf16x8 v;
      #pragma unroll
      for (int j = 0; j < 8; ++j) v[j] = (__bf16)src[i + j];
      *(bf16x8*)(dst + kd + i) = v;
    }
  }
  // permuted biases
  if (gtid < 4u * 2048) {
    unsigned arr = gtid >> 11, rr = gtid & 2047;
    unsigned R = (rr & 3) * 512 + (rr >> 2);
    const float* src = arr == 0 ? p.b_0f : arr == 1 ? p.b_0b : arr == 2 ? p.b_1f : p.b_1b;
    p.bp[arr * 2048 + rr] = src[R];
  }
  // h inits
  if (gtid < 4u * 4096) {
    unsigned dl = gtid >> 12;
    unsigned e = (gtid & 4095) * 8;
    unsigned b = e >> 9, u = e & 511;
    const float* src = p.h0 + (size_t)dl * 64 * 512 + (size_t)b * 512 + u;
    __bf16* dst;
    if (dl == 0)      dst = p.y0 + ((size_t)0 * 64 + b) * 1024 + u;
    else if (dl == 1) dst = p.y0 + ((size_t)513 * 64 + b) * 1024 + 512 + u;
    else if (dl == 2) dst = p.y1f + ((size_t)0 * 64 + b) * 512 + u;
    else              dst = p.h1binit + (size_t)b * 512 + u;
    bf16x8 v;
    #pragma unroll
    for (int j = 0; j < 8; ++j) v[j] = (__bf16)src[j];
    *(bf16x8*)dst = v;
  }

  phase_barrier(p.flags, wg, tid, 1u);

  // Fast path: residue class on ONE XCD + 8 classes on 8 DISTINCT XCDs.
  bool fast;
  {
    const unsigned* xt = p.flags + 512;
    const int r = wg & 7;
    unsigned x0 = xt[r];
    bool ok = true;
    for (int k = 1; k < 32; ++k) ok &= (xt[r + 8 * k] == x0);
    unsigned mask = 0;
    for (int rr = 0; rr < 8; ++rr) mask |= 1u << (xt[rr] & 31);
    ok &= (__popc(mask) == 8);
    fast = ok;
  }

  // ---------------- P1: layer0 recurrence ----------------
  {
    const int g = wg & 7;
    const bool fwd = g < 4;
    const int bg = g & 3;
    const int ug = wg >> 3;
    const int bbase = bg * 16;
    const int uglob = ug * 16 + wv * 4;  // this wave: 4 hidden units
    const int colbase = uglob * 4;       // 16 permuted gate rows
    const __bf16* Wp = fwd ? p.Wp0f : p.Wp0b;
    bf16x8 wfH[16], wfI[8];
    #pragma unroll
    for (int kb = 0; kb < 16; ++kb)
      wfH[kb] = *(const bf16x8*)(Wp + (size_t)(colbase + colq) * 768 + kb * 32 + quad * 8);
    #pragma unroll
    for (int kb = 0; kb < 8; ++kb)
      wfI[kb] = *(const bf16x8*)(Wp + (size_t)(colbase + colq) * 768 + 512 + kb * 32 + quad * 8);
    #pragma unroll
    for (int kb = 0; kb < 16; ++kb) pin(wfH[kb]);
    #pragma unroll
    for (int kb = 0; kb < 8; ++kb) pin(wfI[kb]);
    const f32x4 bias4 = *(const f32x4*)(p.bp + (fwd ? 0 : 1) * 2048 + colbase + quad * 4);
    float c = p.c0[(size_t)(fwd ? 0 : 1) * 64 * 512 +
                   (size_t)(bbase + colq) * 512 + uglob + quad];
    const int dcol = fwd ? 0 : 512;
    unsigned* gfl = p.stepf + (size_t)g * 128 * 16;
    bool alive = true;
    for (int s = 0; s < 512; ++s) {
      const int t = fwd ? s : 511 - s;
      const int slabA = fwd ? t : t + 2;
      const __bf16* aX = p.xT + ((size_t)t * 64 + bbase + colq) * 256 + quad * 8;
      // pre-poll: x-side gates (x is static input)
      f32x4 accX = bias4;
      #pragma unroll
      for (int kb = 0; kb < 8; ++kb) {
        bf16x8 xv = *(const bf16x8*)(aX + kb * 32);
        accX = __builtin_amdgcn_mfma_f32_16x16x32_bf16(wfI[kb], xv, accX, 0, 0, 0);
      }
      if (s > 0 && alive) alive = group_wait128(gfl, lane, (unsigned)s, fast);
      // post-poll: h-side gates (four depth-4 chains)
      const __bf16* aH = p.y0 + ((size_t)slabA * 64 + bbase + colq) * 1024 + dcol + quad * 8;
      f32x4 a0 = {0.f, 0.f, 0.f, 0.f}, a1 = {0.f, 0.f, 0.f, 0.f};
      f32x4 a2 = {0.f, 0.f, 0.f, 0.f}, a3 = {0.f, 0.f, 0.f, 0.f};
      #pragma unroll
      for (int kb = 0; kb < 4; ++kb) {
        a0 = __builtin_amdgcn_mfma_f32_16x16x32_bf16(wfH[kb],      *(const bf16x8*)(aH + kb * 32),        a0, 0, 0, 0);
        a1 = __builtin_amdgcn_mfma_f32_16x16x32_bf16(wfH[4 + kb],  *(const bf16x8*)(aH + (4 + kb) * 32),  a1, 0, 0, 0);
        a2 = __builtin_amdgcn_mfma_f32_16x16x32_bf16(wfH[8 + kb],  *(const bf16x8*)(aH + (8 + kb) * 32),  a2, 0, 0, 0);
        a3 = __builtin_amdgcn_mfma_f32_16x16x32_bf16(wfH[12 + kb], *(const bf16x8*)(aH + (12 + kb) * 32), a3, 0, 0, 0);
      }
      f32x4 g4 = accX + (a0 + a1) + (a2 + a3);
      pointwise_t2(g4, c,
        p.y0 + ((size_t)(t + 1) * 64 + bbase + colq) * 1024 + dcol + uglob + quad, fast);
      if (s < 511) {
        asm volatile("s_waitcnt vmcnt(0)" ::: "memory");  // own h stores at L2/IF
        if (lane == 0)
          flag_store(gfl + (size_t)(ug * 4 + wv) * 16, (unsigned)(s + 1), fast);
      }
    }
  }
  phase_barrier(p.flags, wg, tid, 2u);

  // ---------------- P3: layer1 fwd ((wg&7)<4) | P4: layer1 bwd single step ----
  if ((wg & 7) < 4) {
    const int bg = wg & 7;
    const int ug = wg >> 3;
    const int bbase = bg * 16;
    const int uglob = ug * 16 + wv * 4;
    const int colbase = uglob * 4;
    // weights: wfH[16]+wfX2[16] pinned regs; wfX frags 0..15 -> LDS
    bf16x8 wfH[16], wfX2[16];
    #pragma unroll
    for (int kb = 0; kb < 16; ++kb)
      wfH[kb] = *(const bf16x8*)(p.Wp1f + (size_t)(colbase + colq) * 1536 + kb * 32 + quad * 8);
    {
      const __bf16* wsrc = p.Wp1f + (size_t)(colbase + colq) * 1536 + 512;
      #pragma unroll
      for (int kb = 0; kb < 16; ++kb) {
        bf16x8 w = *(const bf16x8*)(wsrc + kb * 32 + quad * 8);
        *(bf16x8*)(wlds + ((size_t)(wv * 16 + kb) * 64 + lane) * 8) = w;
      }
      #pragma unroll
      for (int kb = 0; kb < 16; ++kb)
        wfX2[kb] = *(const bf16x8*)(wsrc + (16 + kb) * 32 + quad * 8);
    }
    #pragma unroll
    for (int kb = 0; kb < 16; ++kb) pin(wfH[kb]);
    #pragma unroll
    for (int kb = 0; kb < 16; ++kb) pin(wfX2[kb]);
    const f32x4 bias4 = *(const f32x4*)(p.bp + 2 * 2048 + colbase + quad * 4);
    float c = p.c0[(size_t)2 * 64 * 512 +
                   (size_t)(bbase + colq) * 512 + uglob + quad];
    unsigned* gfl = p.stepf + (size_t)(8 + bg) * 128 * 16;
    bool alive = true;
    for (int t = 0; t < 512; ++t) {
      const __bf16* aX = p.y0 + ((size_t)(t + 1) * 64 + bbase + colq) * 1024 + quad * 8;
      // pre-poll: x-side gates (y0 slab t+1 published at phase 2)
      f32x4 accX0 = bias4, accX1 = {0.f, 0.f, 0.f, 0.f};
      #pragma unroll
      for (int kb = 0; kb < 16; ++kb) {
        bf16x8 xv = *(const bf16x8*)(aX + kb * 32);
        bf16x8 wx = *(const bf16x8*)(wlds + ((size_t)(wv * 16 + kb) * 64 + lane) * 8);
        accX0 = __builtin_amdgcn_mfma_f32_16x16x32_bf16(wx, xv, accX0, 0, 0, 0);
      }
      #pragma unroll
      for (int kb = 0; kb < 16; ++kb) {
        bf16x8 xv = *(const bf16x8*)(aX + (16 + kb) * 32);
        accX1 = __builtin_amdgcn_mfma_f32_16x16x32_bf16(wfX2[kb], xv, accX1, 0, 0, 0);
      }
      if (t > 0 && alive) alive = group_wait128(gfl, lane, (unsigned)t, fast);
      // post-poll: h-side gates (four depth-4 chains)
      const __bf16* aH = p.y1f + ((size_t)t * 64 + bbase + colq) * 512 + quad * 8;
      f32x4 a0 = {0.f, 0.f, 0.f, 0.f}, a1 = {0.f, 0.f, 0.f, 0.f};
      f32x4 a2 = {0.f, 0.f, 0.f, 0.f}, a3 = {0.f, 0.f, 0.f, 0.f};
      #pragma unroll
      for (int kb = 0; kb < 4; ++kb) {
        a0 = __builtin_amdgcn_mfma_f32_16x16x32_bf16(wfH[kb],      *(const bf16x8*)(aH + kb * 32),        a0, 0, 0, 0);
        a1 = __builtin_amdgcn_mfma_f32_16x16x32_bf16(wfH[4 + kb],  *(const bf16x8*)(aH + (4 + kb) * 32),  a1, 0, 0, 0);
        a2 = __builtin_amdgcn_mfma_f32_16x16x32_bf16(wfH[8 + kb],  *(const bf16x8*)(aH + (8 + kb) * 32),  a2, 0, 0, 0);
        a3 = __builtin_amdgcn_mfma_f32_16x16x32_bf16(wfH[12 + kb], *(const bf16x8*)(aH + (12 + kb) * 32), a3, 0, 0, 0);
      }
      f32x4 g4 = (accX0 + accX1) + (a0 + a1) + (a2 + a3);
      pointwise_t2(g4, c,
        p.y1f + ((size_t)(t + 1) * 64 + bbase + colq) * 512 + uglob + quad, fast);
      if (t < 511) {
        asm volatile("s_waitcnt vmcnt(0)" ::: "memory");
        if (lane == 0)
          flag_store(gfl + (size_t)(ug * 4 + wv) * 16, (unsigned)(t + 1), fast);
      }
    }
  } else {
    const int bg = (wg & 7) - 4;
    const int ug = wg >> 3;
    const int bbase = bg * 16;
    const int uglob = ug * 16 + wv * 4;
    const int colbase = uglob * 4;
    const __bf16* aH = p.h1binit + (size_t)(bbase + colq) * 512 + quad * 8;
    const __bf16* aX = p.y0 + ((size_t)512 * 64 + bbase + colq) * 1024 + quad * 8;
    const __bf16* wrow = p.Wp1b + (size_t)(colbase + colq) * 1536;
    const f32x4 bias4 = *(const f32x4*)(p.bp + 3 * 2048 + colbase + quad * 4);
    f32x4 accH = bias4;
    f32x4 accX0 = {0.f, 0.f, 0.f, 0.f}, accX1 = {0.f, 0.f, 0.f, 0.f};
    #pragma unroll
    for (int kb = 0; kb < 16; ++kb)
      accH = __builtin_amdgcn_mfma_f32_16x16x32_bf16(*(const bf16x8*)(wrow + kb * 32 + quad * 8),
                                                     *(const bf16x8*)(aH + kb * 32), accH, 0, 0, 0);
    #pragma unroll
    for (int kb = 0; kb < 16; ++kb)
      accX0 = __builtin_amdgcn_mfma_f32_16x16x32_bf16(*(const bf16x8*)(wrow + (16 + kb) * 32 + quad * 8),
                                                      *(const bf16x8*)(aX + kb * 32), accX0, 0, 0, 0);
    #pragma unroll
    for (int kb = 0; kb < 16; ++kb)
      accX1 = __builtin_amdgcn_mfma_f32_16x16x32_bf16(*(const bf16x8*)(wrow + (32 + kb) * 32 + quad * 8),
                                                      *(const bf16x8*)(aX + (16 + kb) * 32), accX1, 0, 0, 0);
    f32x4 g4 = accH + accX0 + accX1;
    float c = p.c0[(size_t)3 * 64 * 512 +
                   (size_t)(bbase + colq) * 512 + uglob + quad];
    pointwise_t2(g4, c,
      p.h1bout + (size_t)(bbase + colq) * 512 + uglob + quad, true);
  }
  phase_barrier(p.flags, wg, tid, 3u);

  // ---------------- FC: out[b][o] = fc_b[o] + last[b,:] . fc_w[o,:] ----------
  if (wg < 8) {
    const int b = wg * 8 + (tid >> 5);
    const int o = (tid >> 2) & 7;
    const int ks = tid & 3;
    const int k0 = ks * 256;
    const __bf16* l1 = p.y1f + ((size_t)512 * 64 + b) * 512;   // h1f(t=511)
    const __bf16* l2 = p.h1bout + (size_t)b * 512;             // h1b(t=511)
    const __bf16* hsrc = (ks < 2) ? (l1 + k0) : (l2 + k0 - 512);
    const float* w = p.fc_w + (size_t)o * 1024 + k0;
    float acc = 0.f;
    for (int k = 0; k < 256; ++k) acc += (float)hsrc[k] * w[k];
    acc += __shfl_down(acc, 2, 4);
    acc += __shfl_down(acc, 1, 4);
    if (ks == 0) p.out[b * 8 + o] = acc + p.fc_b[o];
  }
}

extern "C" void kernel_launch(void* const* d_in, const int* in_sizes, int n_in,
                              void* d_out, int out_size, void* d_ws, size_t ws_size,
                              hipStream_t stream) {
  char* ws = (char*)d_ws;
  Params p;
  p.input_seq = (const float*)d_in[0];
  p.h0 = (const float*)d_in[1];
  p.c0 = (const float*)d_in[2];
  p.w_ih_0f = (const float*)d_in[3];  p.w_hh_0f = (const float*)d_in[4];  p.b_0f = (const float*)d_in[5];
  p.w_ih_0b = (const float*)d_in[6];  p.w_hh_0b = (const float*)d_in[7];  p.b_0b = (const float*)d_in[8];
  p.w_ih_1f = (const float*)d_in[9];  p.w_hh_1f = (const float*)d_in[10]; p.b_1f = (const float*)d_in[11];
  p.w_ih_1b = (const float*)d_in[12]; p.w_hh_1b = (const float*)d_in[13]; p.b_1b = (const float*)d_in[14];
  p.fc_w = (const float*)d_in[15];    p.fc_b = (const float*)d_in[16];
  p.out = (float*)d_out;

  const size_t STEPF_BYTES = (size_t)12 * 128 * 64;  // 98304
  const size_t SYNC_BYTES = 4096 + STEPF_BYTES;
  size_t off = 0;
  p.flags  = (unsigned*)(ws + off); off += 4096;
  p.stepf  = (unsigned*)(ws + off); off += STEPF_BYTES;
  p.xT     = (__bf16*)(ws + off);   off += (size_t)512 * 64 * 256 * 2;
  p.Wp0f   = (__bf16*)(ws + off);   off += (size_t)2048 * 768 * 2;
  p.Wp0b   = (__bf16*)(ws + off);   off += (size_t)2048 * 768 * 2;
  p.Wp1f   = (__bf16*)(ws + off);   off += (size_t)2048 * 1536 * 2;
  p.Wp1b   = (__bf16*)(ws + off);   off += (size_t)2048 * 1536 * 2;
  p.y0     = (__bf16*)(ws + off);   off += (size_t)514 * 64 * 1024 * 2;
  p.y1f    = (__bf16*)(ws + off);   off += (size_t)513 * 64 * 512 * 2;
  p.h1binit= (__bf16*)(ws + off);   off += (size_t)64 * 512 * 2;
  p.h1bout = (__bf16*)(ws + off);   off += (size_t)64 * 512 * 2;
  p.bp     = (float*)(ws + off);    off += (size_t)4 * 2048 * 4;
  (void)ws_size; (void)in_sizes; (void)n_in; (void)out_size;

  hipMemsetAsync(d_ws, 0, SYNC_BYTES, stream);   // zero phase flags + step flags
  lstm_kernel<<<dim3(256), dim3(256), 0, stream>>>(p);
}